// Round 7
// baseline (154.351 us; speedup 1.0000x reference)
//
#include <hip/hip_runtime.h>
#include <math.h>

#define T_SEQ 2048
#define D_MODEL 1024
#define NH 16
#define HD 64

typedef unsigned short ushort_t;
typedef unsigned int uint_t;
typedef short short8 __attribute__((ext_vector_type(8)));
typedef float floatx4 __attribute__((ext_vector_type(4)));

// ---- bf16 helpers (RNE) ----
__device__ __forceinline__ ushort_t f2bf(float f) {
    uint_t u = __float_as_uint(f);
    u += 0x7FFFu + ((u >> 16) & 1u);
    return (ushort_t)(u >> 16);
}
__device__ __forceinline__ uint_t pack2(float a, float b) {
    return (uint_t)f2bf(a) | ((uint_t)f2bf(b) << 16);
}
// copy 16 bf16 (32B) global/LDS (attn Q stage only)
__device__ __forceinline__ void cp16(ushort_t* dst, const ushort_t* src) {
    uint4 a = ((const uint4*)src)[0];
    uint4 b = ((const uint4*)src)[1];
    ((uint4*)dst)[0] = a;
    ((uint4*)dst)[1] = b;
}
// async global -> LDS, 16B per lane (wave-uniform LDS base + lane*16)
__device__ __forceinline__ void gload16(const ushort_t* g, ushort_t* l) {
    __builtin_amdgcn_global_load_lds(
        (const __attribute__((address_space(1))) void*)g,
        (__attribute__((address_space(3))) void*)l, 16, 0, 0);
}

#define LDK 72    // attn Q/P row stride (64 cols + 8 pad)

// ---------------------------------------------------------------------------
// Kernel 0: one-time fp32 -> bf16 convert of x, Wq, Wk, Wv, Wp.
// ---------------------------------------------------------------------------
__global__ __launch_bounds__(256) void to_bf16(
        const float* __restrict__ x,  const float* __restrict__ wq,
        const float* __restrict__ wk, const float* __restrict__ wv,
        const float* __restrict__ wp,
        ushort_t* __restrict__ xb,  ushort_t* __restrict__ wqb,
        ushort_t* __restrict__ wkb, ushort_t* __restrict__ wvb,
        ushort_t* __restrict__ wpb)
{
    size_t i = (size_t)blockIdx.x * 256 + threadIdx.x;
    const float* src; ushort_t* dst; size_t off;
    if (i < 262144)      { src = x;  dst = xb;  off = i; }
    else if (i < 393216) { src = wq; dst = wqb; off = i - 262144; }
    else if (i < 524288) { src = wk; dst = wkb; off = i - 393216; }
    else if (i < 655360) { src = wv; dst = wvb; off = i - 524288; }
    else                 { src = wp; dst = wpb; off = i - 655360; }
    float4 f0 = ((const float4*)src)[off * 2];
    float4 f1 = ((const float4*)src)[off * 2 + 1];
    uint4 u;
    u.x = pack2(f0.x, f0.y); u.y = pack2(f0.z, f0.w);
    u.z = pack2(f1.x, f1.y); u.w = pack2(f1.z, f1.w);
    ((uint4*)dst)[off] = u;
}

// ---------------------------------------------------------------------------
// Kernel 1: QKV GEMM (bf16 MFMA), BM=128 BN=128 BK=64, grid (8,16,3)=384.
// 4 waves, each owns a 64x64 quadrant: acc[4][4], 8 ds_read_b128 per 32 MFMA
// (ratio 0.25 vs 0.75 of the 32x64 tile). 2-phase double-buffered
// global_load_lds staging (8 loads/stage), counted vmcnt(8) + raw s_barrier.
// XOR-swizzle: writer fetches logical slot (tid&7)^(row&7); reader reads
// phys slot (kh*4+quad)^(row&7). FUSED RMSNorm+RoPE (z<2) / V blend (z=2).
// ---------------------------------------------------------------------------
__global__ __launch_bounds__(256) void gemm_qkv(
        const ushort_t* __restrict__ xb,
        const ushort_t* __restrict__ Wqb, const ushort_t* __restrict__ Wkb,
        const ushort_t* __restrict__ Wvb,
        const float* __restrict__ vi, const float* __restrict__ lam,
        ushort_t* __restrict__ qb, ushort_t* __restrict__ kb,
        ushort_t* __restrict__ vbt)
{
    const int z = blockIdx.z;
    const ushort_t* __restrict__ W = (z == 0) ? Wqb : (z == 1) ? Wkb : Wvb;
    const int row0 = blockIdx.y * 128;
    const int col0 = blockIdx.x * 128;

    __shared__ ushort_t As[2 * 128 * 64];    // 32 KB (2 buffers)
    __shared__ ushort_t Bs[2 * 128 * 64];    // 32 KB

    const int tid = threadIdx.x;
    const int wave = tid >> 6, lane = tid & 63;
    const int wm = wave >> 1, wn = wave & 1;
    const int l15 = lane & 15, quad = lane >> 4;
    const int srow  = tid >> 3;                     // staging row 0..31
    const int sslot = (tid & 7) ^ (srow & 7);       // pre-swizzled 16B slot

    floatx4 acc[4][4];
    #pragma unroll
    for (int i = 0; i < 4; ++i)
        #pragma unroll
        for (int j = 0; j < 4; ++j)
            acc[i][j] = (floatx4){0.f, 0.f, 0.f, 0.f};

    // stage tile at k-offset k0 into buffer p (8 gloads/wave)
    auto stageAB = [&](int k0, int p) {
        ushort_t* Ap = As + p * 8192;
        ushort_t* Bp = Bs + p * 8192;
        #pragma unroll
        for (int c = 0; c < 4; ++c)
            gload16(xb + (size_t)(row0 + c * 32 + srow) * D_MODEL + k0 + sslot * 8,
                    Ap + c * 2048 + tid * 8);
        #pragma unroll
        for (int c = 0; c < 4; ++c)
            gload16(W + (size_t)(col0 + c * 32 + srow) * D_MODEL + k0 + sslot * 8,
                    Bp + c * 2048 + tid * 8);
    };

    stageAB(0, 0);
    int cur = 0;
    for (int knext = 64; knext <= D_MODEL; knext += 64) {
        const bool haveNext = (knext < D_MODEL);
        if (haveNext) {
            stageAB(knext, cur ^ 1);
            asm volatile("s_waitcnt vmcnt(8)" ::: "memory");
        } else {
            asm volatile("s_waitcnt vmcnt(0)" ::: "memory");
        }
        __builtin_amdgcn_s_barrier();
        const ushort_t* Ac = As + cur * 8192;
        const ushort_t* Bc = Bs + cur * 8192;
        #pragma unroll
        for (int kh = 0; kh < 2; ++kh) {
            const int slot = ((kh * 4 + quad) ^ (l15 & 7)) << 3;  // ushort offs
            short8 a[4], b[4];
            #pragma unroll
            for (int i = 0; i < 4; ++i)
                a[i] = *(const short8*)(Ac + (64 * wm + i * 16 + l15) * 64 + slot);
            #pragma unroll
            for (int j = 0; j < 4; ++j)
                b[j] = *(const short8*)(Bc + (64 * wn + j * 16 + l15) * 64 + slot);
            #pragma unroll
            for (int i = 0; i < 4; ++i)
                #pragma unroll
                for (int j = 0; j < 4; ++j)
                    acc[i][j] = __builtin_amdgcn_mfma_f32_16x16x32_bf16(a[i], b[j], acc[i][j], 0, 0, 0);
        }
        asm volatile("" ::: "memory");
        __builtin_amdgcn_s_barrier();   // protect buf before next overwrite
        cur ^= 1;
    }

    if (z < 2) {
        ushort_t* __restrict__ o = (z == 0) ? qb : kb;
        const float oscale = (z == 0) ? 0.125f : 1.0f;   // fold 1/sqrt(hd) into q
        const int hbase = col0 + 64 * wn;
        const float eps = 1.1920929e-7f;
        const float fr = exp2f(-10.0f * (float)l15 / 15.0f);  // rotating-pair freq
        #pragma unroll
        for (int i = 0; i < 4; ++i)
            #pragma unroll
            for (int r = 0; r < 4; ++r) {
                const int t = row0 + 64 * wm + i * 16 + quad * 4 + r;
                float v0 = acc[i][0][r], v1 = acc[i][1][r];
                float v2 = acc[i][2][r], v3 = acc[i][3][r];
                float ss = v0 * v0 + v1 * v1 + v2 * v2 + v3 * v3;
                ss += __shfl_xor(ss, 1);
                ss += __shfl_xor(ss, 2);
                ss += __shfl_xor(ss, 4);
                ss += __shfl_xor(ss, 8);
                const float sc = rsqrtf(ss * (1.0f / 64.0f) + eps);
                v0 *= sc; v1 *= sc; v2 *= sc; v3 *= sc;
                const float th = (float)t * fr;
                const float cs = cosf(th), sn = sinf(th);
                const float y0 = v0 * cs + v2 * sn;   // shown-source rotary sign
                const float y2 = v2 * cs - v0 * sn;
                const size_t rb = (size_t)t * D_MODEL + hbase;
                o[rb +  0 + l15] = f2bf(y0 * oscale);
                o[rb + 16 + l15] = f2bf(v1 * oscale);
                o[rb + 32 + l15] = f2bf(y2 * oscale);
                o[rb + 48 + l15] = f2bf(v3 * oscale);
            }
    } else {
        const float l0 = lam[0], l1 = lam[1];
        #pragma unroll
        for (int i = 0; i < 4; ++i)
            #pragma unroll
            for (int j = 0; j < 4; ++j) {
                const int tb = row0 + 64 * wm + i * 16 + quad * 4;
                const int jj = col0 + 64 * wn + j * 16 + l15;
                float b0 = l0 * acc[i][j][0] + l1 * vi[(size_t)(tb + 0) * D_MODEL + jj];
                float b1 = l0 * acc[i][j][1] + l1 * vi[(size_t)(tb + 1) * D_MODEL + jj];
                float b2 = l0 * acc[i][j][2] + l1 * vi[(size_t)(tb + 2) * D_MODEL + jj];
                float b3 = l0 * acc[i][j][3] + l1 * vi[(size_t)(tb + 3) * D_MODEL + jj];
                uint2 u;
                u.x = pack2(b0, b1);
                u.y = pack2(b2, b3);
                *(uint2*)(vbt + (size_t)jj * T_SEQ + tb) = u;   // [d][t]
            }
    }
}

// ---------------------------------------------------------------------------
// Kernel 2: MFMA flash attention, KV-split, FIXED-MAX softmax, 2-phase
// double-buffered K/V via global_load_lds (linear [64][64] + XOR swizzle,
// counted vmcnt(4) + raw s_barrier). |s|<=8 provable => constant max.
// REBALANCED split (makespan 14 sub-tiles, was 16), 54 blocks/head = 864,
// grid (16 h, 54 x) so big blocks dispatch first globally:
//   x in [ 0,28): 2-way chunks of qt = 27 - x/2      (sizes 8..14)
//   x in [28,40): 3-way chunks of qt = 28 + (x-28)/3 (sizes 9..11)
//   x in [40,54): direct qt = 53 - x                 (sizes 14..1, backfill)
// Partials: 40 slots/head (3-way: 0..11, 2-way: 12..39) x 16 heads = 640.
// Opart = 10 MiB dead-ws region; Lpart lives in d_out (scratch until proj).
// ---------------------------------------------------------------------------
__global__ __launch_bounds__(256) void attn(
        const ushort_t* __restrict__ qb, const ushort_t* __restrict__ kb,
        const ushort_t* __restrict__ vbt, ushort_t* __restrict__ yb,
        float* __restrict__ Opart, float* __restrict__ Lpart)
{
    const int h = blockIdx.x;
    const int x = blockIdx.y;
    int qt, ct_begin, ct_end, pidx;
    if (x < 28) {                       // 2-way, qt 27..14
        qt = 27 - (x >> 1);
        const int w = qt + 1;
        const int c0 = (w + 1) >> 1;
        if ((x & 1) == 0) { ct_begin = 0;  ct_end = c0; }
        else              { ct_begin = c0; ct_end = w;  }   // contains diag
        pidx = h * 40 + 12 + (qt - 14) * 2 + (x & 1);
    } else if (x < 40) {                // 3-way, qt 28..31
        const int xx = x - 28;
        qt = 28 + xx / 3;
        const int c = xx % 3;
        const int w = qt + 1;
        const int b0 = (w + 2) / 3;
        const int b1 = (2 * w + 2) / 3;
        ct_begin = (c == 0) ? 0  : (c == 1) ? b0 : b1;
        ct_end   = (c == 0) ? b0 : (c == 1) ? b1 : w;
        pidx = h * 40 + (qt - 28) * 3 + c;
    } else {                            // direct, qt 13..0
        qt = 53 - x;
        ct_begin = 0; ct_end = qt + 1;
        pidx = -1;
    }
    const int t0 = qt * 64;

    __shared__ ushort_t Ks[2 * 64 * 64];   // [s_local][d] linear, swizzled
    __shared__ ushort_t Vs[2 * 64 * 64];   // [d][s_local] linear, swizzled
    __shared__ ushort_t QPs[64 * LDK];     // Q tile, then reused for P

    const int tid = threadIdx.x;
    const int wave = tid >> 6, lane = tid & 63;
    const int l15 = lane & 15, quad = lane >> 4;
    const int r4 = tid >> 2, c4 = (tid & 3) * 16;
    const int srow  = tid >> 3;                   // staging row 0..31
    const int sslot = (tid & 7) ^ (srow & 7);     // pre-swizzled 16B slot
    const int bx = l15 & 7;

    // stage Q (64x64) once
    cp16(QPs + r4 * LDK + c4, qb + (size_t)(t0 + r4) * D_MODEL + h * HD + c4);
    __syncthreads();
    short8 qf[2];
    qf[0] = *(const short8*)(QPs + (16 * wave + l15) * LDK + 0  + quad * 8);
    qf[1] = *(const short8*)(QPs + (16 * wave + l15) * LDK + 32 + quad * 8);

    auto stageKV = [&](int kt, int p) {
        const int s0 = kt * 64;
        ushort_t* Kp = Ks + p * 4096;
        ushort_t* Vp = Vs + p * 4096;
        gload16(kb  + (size_t)(s0 + srow)      * D_MODEL + h * HD + sslot * 8, Kp + tid * 8);
        gload16(kb  + (size_t)(s0 + 32 + srow) * D_MODEL + h * HD + sslot * 8, Kp + 2048 + tid * 8);
        gload16(vbt + (size_t)(h * HD + srow)      * T_SEQ + s0 + sslot * 8,   Vp + tid * 8);
        gload16(vbt + (size_t)(h * HD + 32 + srow) * T_SEQ + s0 + sslot * 8,   Vp + 2048 + tid * 8);
    };

    float l_acc[4];
    floatx4 O[4];
    #pragma unroll
    for (int r = 0; r < 4; ++r) l_acc[r] = 0.0f;
    #pragma unroll
    for (int d = 0; d < 4; ++d) O[d] = (floatx4){0.f, 0.f, 0.f, 0.f};

    stageKV(ct_begin, 0);
    int cur = 0;
    for (int kt = ct_begin; kt < ct_end; ++kt) {
        const bool haveNext = (kt + 1 < ct_end);
        if (haveNext) {
            stageKV(kt + 1, cur ^ 1);
            asm volatile("s_waitcnt vmcnt(4)" ::: "memory");
        } else {
            asm volatile("s_waitcnt vmcnt(0)" ::: "memory");
        }
        __builtin_amdgcn_s_barrier();

        const ushort_t* Kc = Ks + cur * 4096;
        const ushort_t* Vc = Vs + cur * 4096;

        floatx4 sa[4];
        #pragma unroll
        for (int ct = 0; ct < 4; ++ct) {
            const ushort_t* krow = Kc + (ct * 16 + l15) * 64;
            short8 b0 = *(const short8*)(krow + ((quad ^ bx) << 3));
            short8 b1 = *(const short8*)(krow + (((quad + 4) ^ bx) << 3));
            floatx4 t4 = (floatx4){0.f, 0.f, 0.f, 0.f};
            t4 = __builtin_amdgcn_mfma_f32_16x16x32_bf16(qf[0], b0, t4, 0, 0, 0);
            t4 = __builtin_amdgcn_mfma_f32_16x16x32_bf16(qf[1], b1, t4, 0, 0, 0);
            sa[ct] = t4;
        }
        if (kt == qt) {   // causal mask on the diagonal tile
            #pragma unroll
            for (int ct = 0; ct < 4; ++ct)
                #pragma unroll
                for (int r = 0; r < 4; ++r) {
                    int trow = 16 * wave + quad * 4 + r;
                    int scol = ct * 16 + l15;
                    if (scol > trow) sa[ct][r] = -1e30f;
                }
        }
        // fixed-max softmax: p = exp(s - 8), per-lane l accumulation only
        float p[4][4];
        #pragma unroll
        for (int ct = 0; ct < 4; ++ct)
            #pragma unroll
            for (int r = 0; r < 4; ++r) {
                p[ct][r] = __expf(sa[ct][r] - 8.0f);
                l_acc[r] += p[ct][r];
            }

        // P -> LDS (wave-private 16-row stripe; no barrier needed)
        #pragma unroll
        for (int ct = 0; ct < 4; ++ct)
            #pragma unroll
            for (int r = 0; r < 4; ++r)
                QPs[(16 * wave + quad * 4 + r) * LDK + ct * 16 + l15] = f2bf(p[ct][r]);

        short8 pa0 = *(const short8*)(QPs + (16 * wave + l15) * LDK + 0  + quad * 8);
        short8 pa1 = *(const short8*)(QPs + (16 * wave + l15) * LDK + 32 + quad * 8);
        #pragma unroll
        for (int dt = 0; dt < 4; ++dt) {
            const ushort_t* vrow = Vc + (dt * 16 + l15) * 64;
            short8 vb0 = *(const short8*)(vrow + ((quad ^ bx) << 3));
            short8 vb1 = *(const short8*)(vrow + (((quad + 4) ^ bx) << 3));
            O[dt] = __builtin_amdgcn_mfma_f32_16x16x32_bf16(pa0, vb0, O[dt], 0, 0, 0);
            O[dt] = __builtin_amdgcn_mfma_f32_16x16x32_bf16(pa1, vb1, O[dt], 0, 0, 0);
        }

        asm volatile("" ::: "memory");
        __builtin_amdgcn_s_barrier();   // protect buf before next overwrite
        cur ^= 1;
    }

    // one-time row-sum reduce across the 16 col-lanes
    float l_run[4];
    #pragma unroll
    for (int r = 0; r < 4; ++r) {
        float s = l_acc[r];
        s += __shfl_xor(s, 1);
        s += __shfl_xor(s, 2);
        s += __shfl_xor(s, 4);
        s += __shfl_xor(s, 8);
        l_run[r] = s;
    }

    if (pidx < 0) {
        // direct: normalize and write bf16
        #pragma unroll
        for (int r = 0; r < 4; ++r) {
            const float inv_l = 1.0f / l_run[r];
            const int t = t0 + 16 * wave + quad * 4 + r;
            #pragma unroll
            for (int dt = 0; dt < 4; ++dt)
                yb[(size_t)t * D_MODEL + h * HD + dt * 16 + l15] = f2bf(O[dt][r] * inv_l);
        }
    } else {
        // partial: unnormalized fp32 O + per-row l (fixed max => no m needed)
        float* __restrict__ Op = Opart + (size_t)pidx * 4096;
        #pragma unroll
        for (int r = 0; r < 4; ++r) {
            const int row = 16 * wave + quad * 4 + r;
            #pragma unroll
            for (int dt = 0; dt < 4; ++dt)
                Op[row * 64 + dt * 16 + l15] = O[dt][r];
            if (l15 == 0) Lpart[(size_t)pidx * 64 + row] = l_run[r];
        }
    }
}

// ---------------------------------------------------------------------------
// Kernel 2b: combine the 2 or 3 KV-chunk partials for qt in [14,32).
// Fixed max on all chunks => combined = (sum O_c) / (sum l_c).
// grid = (16 h, 18 qt-14). Thread = one (row, 16-col segment).
// ---------------------------------------------------------------------------
__global__ __launch_bounds__(256) void attn_combine(
        const float* __restrict__ Opart, const float* __restrict__ Lpart,
        ushort_t* __restrict__ yb)
{
    const int h  = blockIdx.x;
    const int qt = 14 + (int)blockIdx.y;   // 14..31
    const int tid = threadIdx.x;
    const int row  = tid >> 2;           // 0..63
    const int dseg = (tid & 3) * 16;     // 0/16/32/48
    int s0, nc;
    if (qt >= 28) { s0 = (qt - 28) * 3;        nc = 3; }
    else          { s0 = 12 + (qt - 14) * 2;   nc = 2; }
    const int p0 = h * 40 + s0;

    float accv[16];
    #pragma unroll
    for (int e = 0; e < 16; ++e) accv[e] = 0.0f;
    float lsum = 0.0f;
    for (int c = 0; c < nc; ++c) {
        const float* Op = Opart + (size_t)(p0 + c) * 4096 + row * 64 + dseg;
        lsum += Lpart[(size_t)(p0 + c) * 64 + row];
        #pragma unroll
        for (int g = 0; g < 4; ++g) {
            float4 a = ((const float4*)Op)[g];
            accv[g * 4 + 0] += a.x;
            accv[g * 4 + 1] += a.y;
            accv[g * 4 + 2] += a.z;
            accv[g * 4 + 3] += a.w;
        }
    }
    const float inv = 1.0f / lsum;

    uint_t u[8];
    #pragma unroll
    for (int g = 0; g < 4; ++g) {
        u[g * 2 + 0] = pack2(accv[g * 4 + 0] * inv, accv[g * 4 + 1] * inv);
        u[g * 2 + 1] = pack2(accv[g * 4 + 2] * inv, accv[g * 4 + 3] * inv);
    }
    const int t = qt * 64 + row;
    uint4* dst = (uint4*)(yb + (size_t)t * D_MODEL + h * HD + dseg);
    dst[0] = make_uint4(u[0], u[1], u[2], u[3]);
    dst[1] = make_uint4(u[4], u[5], u[6], u[7]);
}

// ---------------------------------------------------------------------------
// Kernel 3: output projection, BM=128 BN=128 BK=64, grid (8,16) = 128 blocks.
// Same 64x64-per-wave acc[4][4] + 2-phase dbuf global_load_lds. fp32 out.
// ---------------------------------------------------------------------------
__global__ __launch_bounds__(256) void gemm_proj(
        const ushort_t* __restrict__ yb, const ushort_t* __restrict__ Wpb,
        float* __restrict__ out)
{
    const int row0 = blockIdx.y * 128;
    const int col0 = blockIdx.x * 128;

    __shared__ ushort_t As[2 * 128 * 64];
    __shared__ ushort_t Bs[2 * 128 * 64];

    const int tid = threadIdx.x;
    const int wave = tid >> 6, lane = tid & 63;
    const int wm = wave >> 1, wn = wave & 1;
    const int l15 = lane & 15, quad = lane >> 4;
    const int srow  = tid >> 3;
    const int sslot = (tid & 7) ^ (srow & 7);

    floatx4 acc[4][4];
    #pragma unroll
    for (int i = 0; i < 4; ++i)
        #pragma unroll
        for (int j = 0; j < 4; ++j)
            acc[i][j] = (floatx4){0.f, 0.f, 0.f, 0.f};

    auto stageAB = [&](int k0, int p) {
        ushort_t* Ap = As + p * 8192;
        ushort_t* Bp = Bs + p * 8192;
        #pragma unroll
        for (int c = 0; c < 4; ++c)
            gload16(yb + (size_t)(row0 + c * 32 + srow) * D_MODEL + k0 + sslot * 8,
                    Ap + c * 2048 + tid * 8);
        #pragma unroll
        for (int c = 0; c < 4; ++c)
            gload16(Wpb + (size_t)(col0 + c * 32 + srow) * D_MODEL + k0 + sslot * 8,
                    Bp + c * 2048 + tid * 8);
    };

    stageAB(0, 0);
    int cur = 0;
    for (int knext = 64; knext <= D_MODEL; knext += 64) {
        const bool haveNext = (knext < D_MODEL);
        if (haveNext) {
            stageAB(knext, cur ^ 1);
            asm volatile("s_waitcnt vmcnt(8)" ::: "memory");
        } else {
            asm volatile("s_waitcnt vmcnt(0)" ::: "memory");
        }
        __builtin_amdgcn_s_barrier();
        const ushort_t* Ac = As + cur * 8192;
        const ushort_t* Bc = Bs + cur * 8192;
        #pragma unroll
        for (int kh = 0; kh < 2; ++kh) {
            const int slot = ((kh * 4 + quad) ^ (l15 & 7)) << 3;
            short8 a[4], b[4];
            #pragma unroll
            for (int i = 0; i < 4; ++i)
                a[i] = *(const short8*)(Ac + (64 * wm + i * 16 + l15) * 64 + slot);
            #pragma unroll
            for (int j = 0; j < 4; ++j)
                b[j] = *(const short8*)(Bc + (64 * wn + j * 16 + l15) * 64 + slot);
            #pragma unroll
            for (int i = 0; i < 4; ++i)
                #pragma unroll
                for (int j = 0; j < 4; ++j)
                    acc[i][j] = __builtin_amdgcn_mfma_f32_16x16x32_bf16(a[i], b[j], acc[i][j], 0, 0, 0);
        }
        asm volatile("" ::: "memory");
        __builtin_amdgcn_s_barrier();
        cur ^= 1;
    }

    #pragma unroll
    for (int i = 0; i < 4; ++i)
        #pragma unroll
        for (int j = 0; j < 4; ++j) {
            const int t = row0 + 64 * wm + i * 16 + quad * 4;
            const int jj = col0 + 64 * wn + j * 16 + l15;
            #pragma unroll
            for (int r = 0; r < 4; ++r)
                out[(size_t)(t + r) * D_MODEL + jj] = acc[i][j][r];
        }
}

// ---------------------------------------------------------------------------
extern "C" void kernel_launch(void* const* d_in, const int* in_sizes, int n_in,
                              void* d_out, int out_size, void* d_ws, size_t ws_size,
                              hipStream_t stream) {
    (void)in_sizes; (void)n_in; (void)out_size; (void)ws_size;
    const float* x   = (const float*)d_in[0];
    const float* vi  = (const float*)d_in[1];
    const float* Wq  = (const float*)d_in[2];
    const float* Wk  = (const float*)d_in[3];
    const float* Wv  = (const float*)d_in[4];
    const float* Wp  = (const float*)d_in[5];
    const float* lam = (const float*)d_in[6];

    char* base = (char*)d_ws;                                  // 28 MiB used
    ushort_t* xb  = (ushort_t*)(base);                         // [ 0, 4) MiB (dead after gemm_qkv)
    ushort_t* wqb = (ushort_t*)(base + (size_t)4  * 1048576);  // [ 4, 6)  (dead after gemm_qkv)
    ushort_t* wkb = (ushort_t*)(base + (size_t)6  * 1048576);  // [ 6, 8)  (dead after gemm_qkv)
    ushort_t* wvb = (ushort_t*)(base + (size_t)8  * 1048576);  // [ 8,10)  (dead after gemm_qkv)
    ushort_t* wpb = (ushort_t*)(base + (size_t)10 * 1048576);  // [10,12)  (live until gemm_proj)
    ushort_t* qb  = (ushort_t*)(base + (size_t)12 * 1048576);  // [12,16)
    ushort_t* kb  = (ushort_t*)(base + (size_t)16 * 1048576);  // [16,20)
    ushort_t* vbt = (ushort_t*)(base + (size_t)20 * 1048576);  // [20,24)  [d][t]
    ushort_t* yb  = (ushort_t*)(base + (size_t)24 * 1048576);  // [24,28)
    // attn partials: Opart = 640 * 16 KB = 10 MiB in dead [0,10) region;
    // Lpart = 640 * 64 * 4B = 160 KB in d_out (scratch until gemm_proj).
    float* Opart  = (float*)(base);
    float* Lpart  = (float*)d_out;
    float* out = (float*)d_out;

    to_bf16<<<dim3(786432 / 256), 256, 0, stream>>>(x, Wq, Wk, Wv, Wp, xb, wqb, wkb, wvb, wpb);
    gemm_qkv<<<dim3(8, 16, 3), 256, 0, stream>>>(xb, wqb, wkb, wvb, vi, lam, qb, kb, vbt);
    attn<<<dim3(16, 54), 256, 0, stream>>>(qb, kb, vbt, yb, Opart, Lpart);
    attn_combine<<<dim3(16, 18), 256, 0, stream>>>(Opart, Lpart, yb);
    gemm_proj<<<dim3(8, 16), 256, 0, stream>>>(yb, wpb, out);
}

// Round 8
// 144.211 us; speedup vs baseline: 1.0703x; 1.0703x over previous
//
#include <hip/hip_runtime.h>
#include <math.h>

#define T_SEQ 2048
#define D_MODEL 1024
#define NH 16
#define HD 64

typedef unsigned short ushort_t;
typedef unsigned int uint_t;
typedef short short8 __attribute__((ext_vector_type(8)));
typedef float floatx4 __attribute__((ext_vector_type(4)));

// ---- bf16 helpers (RNE) ----
__device__ __forceinline__ ushort_t f2bf(float f) {
    uint_t u = __float_as_uint(f);
    u += 0x7FFFu + ((u >> 16) & 1u);
    return (ushort_t)(u >> 16);
}
__device__ __forceinline__ uint_t pack2(float a, float b) {
    return (uint_t)f2bf(a) | ((uint_t)f2bf(b) << 16);
}
// copy 16 bf16 (32B) global/LDS (attn Q stage only)
__device__ __forceinline__ void cp16(ushort_t* dst, const ushort_t* src) {
    uint4 a = ((const uint4*)src)[0];
    uint4 b = ((const uint4*)src)[1];
    ((uint4*)dst)[0] = a;
    ((uint4*)dst)[1] = b;
}
// async global -> LDS, 16B per lane (wave-uniform LDS base + lane*16)
__device__ __forceinline__ void gload16(const ushort_t* g, ushort_t* l) {
    __builtin_amdgcn_global_load_lds(
        (const __attribute__((address_space(1))) void*)g,
        (__attribute__((address_space(3))) void*)l, 16, 0, 0);
}

#define LDK 72    // attn Q/P row stride (64 cols + 8 pad)

// ---------------------------------------------------------------------------
// Kernel 0: one-time fp32 -> bf16 convert of x, Wq, Wk, Wv, Wp.
// ---------------------------------------------------------------------------
__global__ __launch_bounds__(256) void to_bf16(
        const float* __restrict__ x,  const float* __restrict__ wq,
        const float* __restrict__ wk, const float* __restrict__ wv,
        const float* __restrict__ wp,
        ushort_t* __restrict__ xb,  ushort_t* __restrict__ wqb,
        ushort_t* __restrict__ wkb, ushort_t* __restrict__ wvb,
        ushort_t* __restrict__ wpb)
{
    size_t i = (size_t)blockIdx.x * 256 + threadIdx.x;
    const float* src; ushort_t* dst; size_t off;
    if (i < 262144)      { src = x;  dst = xb;  off = i; }
    else if (i < 393216) { src = wq; dst = wqb; off = i - 262144; }
    else if (i < 524288) { src = wk; dst = wkb; off = i - 393216; }
    else if (i < 655360) { src = wv; dst = wvb; off = i - 524288; }
    else                 { src = wp; dst = wpb; off = i - 655360; }
    float4 f0 = ((const float4*)src)[off * 2];
    float4 f1 = ((const float4*)src)[off * 2 + 1];
    uint4 u;
    u.x = pack2(f0.x, f0.y); u.y = pack2(f0.z, f0.w);
    u.z = pack2(f1.x, f1.y); u.w = pack2(f1.z, f1.w);
    ((uint4*)dst)[off] = u;
}

// ---------------------------------------------------------------------------
// Kernel 1: QKV GEMM (bf16 MFMA), BM=64 BN=128 BK=64, grid (8,32,3) = 768
// blocks = 3/CU (REVERTED from 128x128/384: that halved memory concurrency
// and tripled duration — this kernel is latency-bound, not LDS-read-bound).
// 2-phase double-buffered global_load_lds, counted vmcnt(6) + raw s_barrier.
// XOR-swizzle: writer fetches logical slot (tid&7)^(row&7); reader reads
// phys slot (kh*4+quad)^(row&7). FUSED RMSNorm+RoPE (z<2) / V blend (z=2).
// ---------------------------------------------------------------------------
__global__ __launch_bounds__(256) void gemm_qkv(
        const ushort_t* __restrict__ xb,
        const ushort_t* __restrict__ Wqb, const ushort_t* __restrict__ Wkb,
        const ushort_t* __restrict__ Wvb,
        const float* __restrict__ vi, const float* __restrict__ lam,
        ushort_t* __restrict__ qb, ushort_t* __restrict__ kb,
        ushort_t* __restrict__ vbt)
{
    const int z = blockIdx.z;
    const ushort_t* __restrict__ W = (z == 0) ? Wqb : (z == 1) ? Wkb : Wvb;
    const int row0 = blockIdx.y * 64;
    const int col0 = blockIdx.x * 128;

    __shared__ ushort_t As[2 * 64 * 64];     // 16 KB (2 buffers)
    __shared__ ushort_t Bs[2 * 128 * 64];    // 32 KB

    const int tid = threadIdx.x;
    const int wave = tid >> 6, lane = tid & 63;
    const int wm = wave >> 1, wn = wave & 1;
    const int l15 = lane & 15, quad = lane >> 4;
    const int srow  = tid >> 3;                     // staging row 0..31
    const int sslot = (tid & 7) ^ (srow & 7);       // pre-swizzled 16B slot

    floatx4 acc[2][4];
    #pragma unroll
    for (int i = 0; i < 2; ++i)
        #pragma unroll
        for (int j = 0; j < 4; ++j)
            acc[i][j] = (floatx4){0.f, 0.f, 0.f, 0.f};

    // stage tile at k-offset k0 into buffer p (6 gloads/wave)
    auto stageAB = [&](int k0, int p) {
        ushort_t* Ap = As + p * 4096;
        ushort_t* Bp = Bs + p * 8192;
        #pragma unroll
        for (int c = 0; c < 2; ++c)
            gload16(xb + (size_t)(row0 + c * 32 + srow) * D_MODEL + k0 + sslot * 8,
                    Ap + c * 2048 + tid * 8);
        #pragma unroll
        for (int c = 0; c < 4; ++c)
            gload16(W + (size_t)(col0 + c * 32 + srow) * D_MODEL + k0 + sslot * 8,
                    Bp + c * 2048 + tid * 8);
    };

    stageAB(0, 0);
    int cur = 0;
    for (int knext = 64; knext <= D_MODEL; knext += 64) {
        const bool haveNext = (knext < D_MODEL);
        if (haveNext) {
            stageAB(knext, cur ^ 1);
            asm volatile("s_waitcnt vmcnt(6)" ::: "memory");
        } else {
            asm volatile("s_waitcnt vmcnt(0)" ::: "memory");
        }
        __builtin_amdgcn_s_barrier();
        const ushort_t* Ac = As + cur * 4096;
        const ushort_t* Bc = Bs + cur * 8192;
        #pragma unroll
        for (int kh = 0; kh < 2; ++kh) {
            const int slot = ((kh * 4 + quad) ^ (l15 & 7)) << 3;  // ushort offs
            short8 a[2], b[4];
            #pragma unroll
            for (int i = 0; i < 2; ++i)
                a[i] = *(const short8*)(Ac + (32 * wm + i * 16 + l15) * 64 + slot);
            #pragma unroll
            for (int j = 0; j < 4; ++j)
                b[j] = *(const short8*)(Bc + (64 * wn + j * 16 + l15) * 64 + slot);
            #pragma unroll
            for (int i = 0; i < 2; ++i)
                #pragma unroll
                for (int j = 0; j < 4; ++j)
                    acc[i][j] = __builtin_amdgcn_mfma_f32_16x16x32_bf16(a[i], b[j], acc[i][j], 0, 0, 0);
        }
        asm volatile("" ::: "memory");
        __builtin_amdgcn_s_barrier();   // protect buf before next overwrite
        cur ^= 1;
    }

    if (z < 2) {
        ushort_t* __restrict__ o = (z == 0) ? qb : kb;
        const float oscale = (z == 0) ? 0.125f : 1.0f;   // fold 1/sqrt(hd) into q
        const int hbase = col0 + 64 * wn;
        const float eps = 1.1920929e-7f;
        const float fr = exp2f(-10.0f * (float)l15 / 15.0f);  // rotating-pair freq
        #pragma unroll
        for (int i = 0; i < 2; ++i)
            #pragma unroll
            for (int r = 0; r < 4; ++r) {
                const int t = row0 + 32 * wm + i * 16 + quad * 4 + r;
                float v0 = acc[i][0][r], v1 = acc[i][1][r];
                float v2 = acc[i][2][r], v3 = acc[i][3][r];
                float ss = v0 * v0 + v1 * v1 + v2 * v2 + v3 * v3;
                ss += __shfl_xor(ss, 1);
                ss += __shfl_xor(ss, 2);
                ss += __shfl_xor(ss, 4);
                ss += __shfl_xor(ss, 8);
                const float sc = rsqrtf(ss * (1.0f / 64.0f) + eps);
                v0 *= sc; v1 *= sc; v2 *= sc; v3 *= sc;
                const float th = (float)t * fr;
                const float cs = cosf(th), sn = sinf(th);
                const float y0 = v0 * cs + v2 * sn;   // shown-source rotary sign
                const float y2 = v2 * cs - v0 * sn;
                const size_t rb = (size_t)t * D_MODEL + hbase;
                o[rb +  0 + l15] = f2bf(y0 * oscale);
                o[rb + 16 + l15] = f2bf(v1 * oscale);
                o[rb + 32 + l15] = f2bf(y2 * oscale);
                o[rb + 48 + l15] = f2bf(v3 * oscale);
            }
    } else {
        const float l0 = lam[0], l1 = lam[1];
        #pragma unroll
        for (int i = 0; i < 2; ++i)
            #pragma unroll
            for (int j = 0; j < 4; ++j) {
                const int tb = row0 + 32 * wm + i * 16 + quad * 4;
                const int jj = col0 + 64 * wn + j * 16 + l15;
                float b0 = l0 * acc[i][j][0] + l1 * vi[(size_t)(tb + 0) * D_MODEL + jj];
                float b1 = l0 * acc[i][j][1] + l1 * vi[(size_t)(tb + 1) * D_MODEL + jj];
                float b2 = l0 * acc[i][j][2] + l1 * vi[(size_t)(tb + 2) * D_MODEL + jj];
                float b3 = l0 * acc[i][j][3] + l1 * vi[(size_t)(tb + 3) * D_MODEL + jj];
                uint2 u;
                u.x = pack2(b0, b1);
                u.y = pack2(b2, b3);
                *(uint2*)(vbt + (size_t)jj * T_SEQ + tb) = u;   // [d][t]
            }
    }
}

// ---------------------------------------------------------------------------
// Kernel 2: MFMA flash attention, KV-split, FIXED-MAX softmax, 2-phase
// double-buffered K/V via global_load_lds (linear [64][64] + XOR swizzle,
// counted vmcnt(4) + raw s_barrier). |s|<=8 provable => constant max.
// REBALANCED split (makespan 14 sub-tiles), 54 blocks/head = 864,
// grid (16 h, 54 x) so big blocks dispatch first globally:
//   x in [ 0,28): 2-way chunks of qt = 27 - x/2      (sizes 8..14)
//   x in [28,40): 3-way chunks of qt = 28 + (x-28)/3 (sizes 9..11)
//   x in [40,54): direct qt = 53 - x                 (sizes 14..1, backfill)
// Partials: 40 slots/head (3-way: 0..11, 2-way: 12..39) x 16 heads = 640.
// Opart = 10 MiB dead-ws region; Lpart lives in d_out (scratch until proj).
// ---------------------------------------------------------------------------
__global__ __launch_bounds__(256) void attn(
        const ushort_t* __restrict__ qb, const ushort_t* __restrict__ kb,
        const ushort_t* __restrict__ vbt, ushort_t* __restrict__ yb,
        float* __restrict__ Opart, float* __restrict__ Lpart)
{
    const int h = blockIdx.x;
    const int x = blockIdx.y;
    int qt, ct_begin, ct_end, pidx;
    if (x < 28) {                       // 2-way, qt 27..14
        qt = 27 - (x >> 1);
        const int w = qt + 1;
        const int c0 = (w + 1) >> 1;
        if ((x & 1) == 0) { ct_begin = 0;  ct_end = c0; }
        else              { ct_begin = c0; ct_end = w;  }   // contains diag
        pidx = h * 40 + 12 + (qt - 14) * 2 + (x & 1);
    } else if (x < 40) {                // 3-way, qt 28..31
        const int xx = x - 28;
        qt = 28 + xx / 3;
        const int c = xx % 3;
        const int w = qt + 1;
        const int b0 = (w + 2) / 3;
        const int b1 = (2 * w + 2) / 3;
        ct_begin = (c == 0) ? 0  : (c == 1) ? b0 : b1;
        ct_end   = (c == 0) ? b0 : (c == 1) ? b1 : w;
        pidx = h * 40 + (qt - 28) * 3 + c;
    } else {                            // direct, qt 13..0
        qt = 53 - x;
        ct_begin = 0; ct_end = qt + 1;
        pidx = -1;
    }
    const int t0 = qt * 64;

    __shared__ ushort_t Ks[2 * 64 * 64];   // [s_local][d] linear, swizzled
    __shared__ ushort_t Vs[2 * 64 * 64];   // [d][s_local] linear, swizzled
    __shared__ ushort_t QPs[64 * LDK];     // Q tile, then reused for P

    const int tid = threadIdx.x;
    const int wave = tid >> 6, lane = tid & 63;
    const int l15 = lane & 15, quad = lane >> 4;
    const int r4 = tid >> 2, c4 = (tid & 3) * 16;
    const int srow  = tid >> 3;                   // staging row 0..31
    const int sslot = (tid & 7) ^ (srow & 7);     // pre-swizzled 16B slot
    const int bx = l15 & 7;

    // stage Q (64x64) once
    cp16(QPs + r4 * LDK + c4, qb + (size_t)(t0 + r4) * D_MODEL + h * HD + c4);
    __syncthreads();
    short8 qf[2];
    qf[0] = *(const short8*)(QPs + (16 * wave + l15) * LDK + 0  + quad * 8);
    qf[1] = *(const short8*)(QPs + (16 * wave + l15) * LDK + 32 + quad * 8);

    auto stageKV = [&](int kt, int p) {
        const int s0 = kt * 64;
        ushort_t* Kp = Ks + p * 4096;
        ushort_t* Vp = Vs + p * 4096;
        gload16(kb  + (size_t)(s0 + srow)      * D_MODEL + h * HD + sslot * 8, Kp + tid * 8);
        gload16(kb  + (size_t)(s0 + 32 + srow) * D_MODEL + h * HD + sslot * 8, Kp + 2048 + tid * 8);
        gload16(vbt + (size_t)(h * HD + srow)      * T_SEQ + s0 + sslot * 8,   Vp + tid * 8);
        gload16(vbt + (size_t)(h * HD + 32 + srow) * T_SEQ + s0 + sslot * 8,   Vp + 2048 + tid * 8);
    };

    float l_acc[4];
    floatx4 O[4];
    #pragma unroll
    for (int r = 0; r < 4; ++r) l_acc[r] = 0.0f;
    #pragma unroll
    for (int d = 0; d < 4; ++d) O[d] = (floatx4){0.f, 0.f, 0.f, 0.f};

    stageKV(ct_begin, 0);
    int cur = 0;
    for (int kt = ct_begin; kt < ct_end; ++kt) {
        const bool haveNext = (kt + 1 < ct_end);
        if (haveNext) {
            stageKV(kt + 1, cur ^ 1);
            asm volatile("s_waitcnt vmcnt(4)" ::: "memory");
        } else {
            asm volatile("s_waitcnt vmcnt(0)" ::: "memory");
        }
        __builtin_amdgcn_s_barrier();

        const ushort_t* Kc = Ks + cur * 4096;
        const ushort_t* Vc = Vs + cur * 4096;

        floatx4 sa[4];
        #pragma unroll
        for (int ct = 0; ct < 4; ++ct) {
            const ushort_t* krow = Kc + (ct * 16 + l15) * 64;
            short8 b0 = *(const short8*)(krow + ((quad ^ bx) << 3));
            short8 b1 = *(const short8*)(krow + (((quad + 4) ^ bx) << 3));
            floatx4 t4 = (floatx4){0.f, 0.f, 0.f, 0.f};
            t4 = __builtin_amdgcn_mfma_f32_16x16x32_bf16(qf[0], b0, t4, 0, 0, 0);
            t4 = __builtin_amdgcn_mfma_f32_16x16x32_bf16(qf[1], b1, t4, 0, 0, 0);
            sa[ct] = t4;
        }
        if (kt == qt) {   // causal mask on the diagonal tile
            #pragma unroll
            for (int ct = 0; ct < 4; ++ct)
                #pragma unroll
                for (int r = 0; r < 4; ++r) {
                    int trow = 16 * wave + quad * 4 + r;
                    int scol = ct * 16 + l15;
                    if (scol > trow) sa[ct][r] = -1e30f;
                }
        }
        // fixed-max softmax: p = exp(s - 8), per-lane l accumulation only
        float p[4][4];
        #pragma unroll
        for (int ct = 0; ct < 4; ++ct)
            #pragma unroll
            for (int r = 0; r < 4; ++r) {
                p[ct][r] = __expf(sa[ct][r] - 8.0f);
                l_acc[r] += p[ct][r];
            }

        // P -> LDS (wave-private 16-row stripe; no barrier needed)
        #pragma unroll
        for (int ct = 0; ct < 4; ++ct)
            #pragma unroll
            for (int r = 0; r < 4; ++r)
                QPs[(16 * wave + quad * 4 + r) * LDK + ct * 16 + l15] = f2bf(p[ct][r]);

        short8 pa0 = *(const short8*)(QPs + (16 * wave + l15) * LDK + 0  + quad * 8);
        short8 pa1 = *(const short8*)(QPs + (16 * wave + l15) * LDK + 32 + quad * 8);
        #pragma unroll
        for (int dt = 0; dt < 4; ++dt) {
            const ushort_t* vrow = Vc + (dt * 16 + l15) * 64;
            short8 vb0 = *(const short8*)(vrow + ((quad ^ bx) << 3));
            short8 vb1 = *(const short8*)(vrow + (((quad + 4) ^ bx) << 3));
            O[dt] = __builtin_amdgcn_mfma_f32_16x16x32_bf16(pa0, vb0, O[dt], 0, 0, 0);
            O[dt] = __builtin_amdgcn_mfma_f32_16x16x32_bf16(pa1, vb1, O[dt], 0, 0, 0);
        }

        asm volatile("" ::: "memory");
        __builtin_amdgcn_s_barrier();   // protect buf before next overwrite
        cur ^= 1;
    }

    // one-time row-sum reduce across the 16 col-lanes
    float l_run[4];
    #pragma unroll
    for (int r = 0; r < 4; ++r) {
        float s = l_acc[r];
        s += __shfl_xor(s, 1);
        s += __shfl_xor(s, 2);
        s += __shfl_xor(s, 4);
        s += __shfl_xor(s, 8);
        l_run[r] = s;
    }

    if (pidx < 0) {
        // direct: normalize and write bf16
        #pragma unroll
        for (int r = 0; r < 4; ++r) {
            const float inv_l = 1.0f / l_run[r];
            const int t = t0 + 16 * wave + quad * 4 + r;
            #pragma unroll
            for (int dt = 0; dt < 4; ++dt)
                yb[(size_t)t * D_MODEL + h * HD + dt * 16 + l15] = f2bf(O[dt][r] * inv_l);
        }
    } else {
        // partial: unnormalized fp32 O + per-row l (fixed max => no m needed)
        float* __restrict__ Op = Opart + (size_t)pidx * 4096;
        #pragma unroll
        for (int r = 0; r < 4; ++r) {
            const int row = 16 * wave + quad * 4 + r;
            #pragma unroll
            for (int dt = 0; dt < 4; ++dt)
                Op[row * 64 + dt * 16 + l15] = O[dt][r];
            if (l15 == 0) Lpart[(size_t)pidx * 64 + row] = l_run[r];
        }
    }
}

// ---------------------------------------------------------------------------
// Kernel 2b: combine the 2 or 3 KV-chunk partials for qt in [14,32).
// Fixed max on all chunks => combined = (sum O_c) / (sum l_c).
// grid = (16 h, 18 qt-14). Thread = one (row, 16-col segment).
// ---------------------------------------------------------------------------
__global__ __launch_bounds__(256) void attn_combine(
        const float* __restrict__ Opart, const float* __restrict__ Lpart,
        ushort_t* __restrict__ yb)
{
    const int h  = blockIdx.x;
    const int qt = 14 + (int)blockIdx.y;   // 14..31
    const int tid = threadIdx.x;
    const int row  = tid >> 2;           // 0..63
    const int dseg = (tid & 3) * 16;     // 0/16/32/48
    int s0, nc;
    if (qt >= 28) { s0 = (qt - 28) * 3;        nc = 3; }
    else          { s0 = 12 + (qt - 14) * 2;   nc = 2; }
    const int p0 = h * 40 + s0;

    float accv[16];
    #pragma unroll
    for (int e = 0; e < 16; ++e) accv[e] = 0.0f;
    float lsum = 0.0f;
    for (int c = 0; c < nc; ++c) {
        const float* Op = Opart + (size_t)(p0 + c) * 4096 + row * 64 + dseg;
        lsum += Lpart[(size_t)(p0 + c) * 64 + row];
        #pragma unroll
        for (int g = 0; g < 4; ++g) {
            float4 a = ((const float4*)Op)[g];
            accv[g * 4 + 0] += a.x;
            accv[g * 4 + 1] += a.y;
            accv[g * 4 + 2] += a.z;
            accv[g * 4 + 3] += a.w;
        }
    }
    const float inv = 1.0f / lsum;

    uint_t u[8];
    #pragma unroll
    for (int g = 0; g < 4; ++g) {
        u[g * 2 + 0] = pack2(accv[g * 4 + 0] * inv, accv[g * 4 + 1] * inv);
        u[g * 2 + 1] = pack2(accv[g * 4 + 2] * inv, accv[g * 4 + 3] * inv);
    }
    const int t = qt * 64 + row;
    uint4* dst = (uint4*)(yb + (size_t)t * D_MODEL + h * HD + dseg);
    dst[0] = make_uint4(u[0], u[1], u[2], u[3]);
    dst[1] = make_uint4(u[4], u[5], u[6], u[7]);
}

// ---------------------------------------------------------------------------
// Kernel 3: output projection, BM=64 BN=128 BK=64, grid (8,32) = 256 blocks
// = 1/CU (REVERTED from 128x128/128-block). Same 2-phase dbuf staging.
// ---------------------------------------------------------------------------
__global__ __launch_bounds__(256) void gemm_proj(
        const ushort_t* __restrict__ yb, const ushort_t* __restrict__ Wpb,
        float* __restrict__ out)
{
    const int row0 = blockIdx.y * 64;
    const int col0 = blockIdx.x * 128;

    __shared__ ushort_t As[2 * 64 * 64];
    __shared__ ushort_t Bs[2 * 128 * 64];

    const int tid = threadIdx.x;
    const int wave = tid >> 6, lane = tid & 63;
    const int wm = wave >> 1, wn = wave & 1;
    const int l15 = lane & 15, quad = lane >> 4;
    const int srow  = tid >> 3;
    const int sslot = (tid & 7) ^ (srow & 7);

    floatx4 acc[2][4];
    #pragma unroll
    for (int i = 0; i < 2; ++i)
        #pragma unroll
        for (int j = 0; j < 4; ++j)
            acc[i][j] = (floatx4){0.f, 0.f, 0.f, 0.f};

    auto stageAB = [&](int k0, int p) {
        ushort_t* Ap = As + p * 4096;
        ushort_t* Bp = Bs + p * 8192;
        #pragma unroll
        for (int c = 0; c < 2; ++c)
            gload16(yb + (size_t)(row0 + c * 32 + srow) * D_MODEL + k0 + sslot * 8,
                    Ap + c * 2048 + tid * 8);
        #pragma unroll
        for (int c = 0; c < 4; ++c)
            gload16(Wpb + (size_t)(col0 + c * 32 + srow) * D_MODEL + k0 + sslot * 8,
                    Bp + c * 2048 + tid * 8);
    };

    stageAB(0, 0);
    int cur = 0;
    for (int knext = 64; knext <= D_MODEL; knext += 64) {
        const bool haveNext = (knext < D_MODEL);
        if (haveNext) {
            stageAB(knext, cur ^ 1);
            asm volatile("s_waitcnt vmcnt(6)" ::: "memory");
        } else {
            asm volatile("s_waitcnt vmcnt(0)" ::: "memory");
        }
        __builtin_amdgcn_s_barrier();
        const ushort_t* Ac = As + cur * 4096;
        const ushort_t* Bc = Bs + cur * 8192;
        #pragma unroll
        for (int kh = 0; kh < 2; ++kh) {
            const int slot = ((kh * 4 + quad) ^ (l15 & 7)) << 3;
            short8 a[2], b[4];
            #pragma unroll
            for (int i = 0; i < 2; ++i)
                a[i] = *(const short8*)(Ac + (32 * wm + i * 16 + l15) * 64 + slot);
            #pragma unroll
            for (int j = 0; j < 4; ++j)
                b[j] = *(const short8*)(Bc + (64 * wn + j * 16 + l15) * 64 + slot);
            #pragma unroll
            for (int i = 0; i < 2; ++i)
                #pragma unroll
                for (int j = 0; j < 4; ++j)
                    acc[i][j] = __builtin_amdgcn_mfma_f32_16x16x32_bf16(a[i], b[j], acc[i][j], 0, 0, 0);
        }
        asm volatile("" ::: "memory");
        __builtin_amdgcn_s_barrier();
        cur ^= 1;
    }

    #pragma unroll
    for (int i = 0; i < 2; ++i)
        #pragma unroll
        for (int j = 0; j < 4; ++j) {
            const int t = row0 + 32 * wm + i * 16 + quad * 4;
            const int jj = col0 + 64 * wn + j * 16 + l15;
            #pragma unroll
            for (int r = 0; r < 4; ++r)
                out[(size_t)(t + r) * D_MODEL + jj] = acc[i][j][r];
        }
}

// ---------------------------------------------------------------------------
extern "C" void kernel_launch(void* const* d_in, const int* in_sizes, int n_in,
                              void* d_out, int out_size, void* d_ws, size_t ws_size,
                              hipStream_t stream) {
    (void)in_sizes; (void)n_in; (void)out_size; (void)ws_size;
    const float* x   = (const float*)d_in[0];
    const float* vi  = (const float*)d_in[1];
    const float* Wq  = (const float*)d_in[2];
    const float* Wk  = (const float*)d_in[3];
    const float* Wv  = (const float*)d_in[4];
    const float* Wp  = (const float*)d_in[5];
    const float* lam = (const float*)d_in[6];

    char* base = (char*)d_ws;                                  // 28 MiB used
    ushort_t* xb  = (ushort_t*)(base);                         // [ 0, 4) MiB (dead after gemm_qkv)
    ushort_t* wqb = (ushort_t*)(base + (size_t)4  * 1048576);  // [ 4, 6)  (dead after gemm_qkv)
    ushort_t* wkb = (ushort_t*)(base + (size_t)6  * 1048576);  // [ 6, 8)  (dead after gemm_qkv)
    ushort_t* wvb = (ushort_t*)(base + (size_t)8  * 1048576);  // [ 8,10)  (dead after gemm_qkv)
    ushort_t* wpb = (ushort_t*)(base + (size_t)10 * 1048576);  // [10,12)  (live until gemm_proj)
    ushort_t* qb  = (ushort_t*)(base + (size_t)12 * 1048576);  // [12,16)
    ushort_t* kb  = (ushort_t*)(base + (size_t)16 * 1048576);  // [16,20)
    ushort_t* vbt = (ushort_t*)(base + (size_t)20 * 1048576);  // [20,24)  [d][t]
    ushort_t* yb  = (ushort_t*)(base + (size_t)24 * 1048576);  // [24,28)
    // attn partials: Opart = 640 * 16 KB = 10 MiB in dead [0,10) region;
    // Lpart = 640 * 64 * 4B = 160 KB in d_out (scratch until gemm_proj).
    float* Opart  = (float*)(base);
    float* Lpart  = (float*)d_out;
    float* out = (float*)d_out;

    to_bf16<<<dim3(786432 / 256), 256, 0, stream>>>(x, Wq, Wk, Wv, Wp, xb, wqb, wkb, wvb, wpb);
    gemm_qkv<<<dim3(8, 32, 3), 256, 0, stream>>>(xb, wqb, wkb, wvb, vi, lam, qb, kb, vbt);
    attn<<<dim3(16, 54), 256, 0, stream>>>(qb, kb, vbt, yb, Opart, Lpart);
    attn_combine<<<dim3(16, 18), 256, 0, stream>>>(Opart, Lpart, yb);
    gemm_proj<<<dim3(8, 32), 256, 0, stream>>>(yb, wpb, out);
}

// Round 9
// 144.156 us; speedup vs baseline: 1.0707x; 1.0004x over previous
//
#include <hip/hip_runtime.h>
#include <math.h>

#define T_SEQ 2048
#define D_MODEL 1024
#define NH 16
#define HD 64

typedef unsigned short ushort_t;
typedef unsigned int uint_t;
typedef short short8 __attribute__((ext_vector_type(8)));
typedef float floatx4 __attribute__((ext_vector_type(4)));

// ---- bf16 helpers (RNE) ----
__device__ __forceinline__ ushort_t f2bf(float f) {
    uint_t u = __float_as_uint(f);
    u += 0x7FFFu + ((u >> 16) & 1u);
    return (ushort_t)(u >> 16);
}
__device__ __forceinline__ uint_t pack2(float a, float b) {
    return (uint_t)f2bf(a) | ((uint_t)f2bf(b) << 16);
}
// copy 16 bf16 (32B) global/LDS (attn Q stage only)
__device__ __forceinline__ void cp16(ushort_t* dst, const ushort_t* src) {
    uint4 a = ((const uint4*)src)[0];
    uint4 b = ((const uint4*)src)[1];
    ((uint4*)dst)[0] = a;
    ((uint4*)dst)[1] = b;
}
// async global -> LDS, 16B per lane (wave-uniform LDS base + lane*16)
__device__ __forceinline__ void gload16(const ushort_t* g, ushort_t* l) {
    __builtin_amdgcn_global_load_lds(
        (const __attribute__((address_space(1))) void*)g,
        (__attribute__((address_space(3))) void*)l, 16, 0, 0);
}

#define LDK 72    // attn Q/P row stride (64 cols + 8 pad)

// ---------------------------------------------------------------------------
// Kernel 0: one-time fp32 -> bf16 convert of x, Wq, Wk, Wv, Wp.
// ---------------------------------------------------------------------------
__global__ __launch_bounds__(256) void to_bf16(
        const float* __restrict__ x,  const float* __restrict__ wq,
        const float* __restrict__ wk, const float* __restrict__ wv,
        const float* __restrict__ wp,
        ushort_t* __restrict__ xb,  ushort_t* __restrict__ wqb,
        ushort_t* __restrict__ wkb, ushort_t* __restrict__ wvb,
        ushort_t* __restrict__ wpb)
{
    size_t i = (size_t)blockIdx.x * 256 + threadIdx.x;
    const float* src; ushort_t* dst; size_t off;
    if (i < 262144)      { src = x;  dst = xb;  off = i; }
    else if (i < 393216) { src = wq; dst = wqb; off = i - 262144; }
    else if (i < 524288) { src = wk; dst = wkb; off = i - 393216; }
    else if (i < 655360) { src = wv; dst = wvb; off = i - 524288; }
    else                 { src = wp; dst = wpb; off = i - 655360; }
    float4 f0 = ((const float4*)src)[off * 2];
    float4 f1 = ((const float4*)src)[off * 2 + 1];
    uint4 u;
    u.x = pack2(f0.x, f0.y); u.y = pack2(f0.z, f0.w);
    u.z = pack2(f1.x, f1.y); u.w = pack2(f1.z, f1.w);
    ((uint4*)dst)[off] = u;
}

// ---------------------------------------------------------------------------
// Kernel 1: QKV GEMM (bf16 MFMA), BM=64 BN=128 BK=64, grid (8,32,3) = 768
// blocks = 3/CU. 2-phase dbuf with DS-READ-FIRST ordering: every ds_read of
// the current buffer precedes the next-tile global_load_lds issue in program
// order, so SIInsertWaitcnts cannot insert a conservative vmcnt(0) (LDS-DMA
// alias) before them. Top-of-iter vmcnt(0) waits only for loads issued one
// full iteration ago. ONE barrier per iteration (reads land in regs before
// any wave reaches the next top barrier). sched_barrier(0) pins regions.
// XOR-swizzle: writer fetches logical slot (tid&7)^(row&7); reader reads
// phys slot (kh*4+quad)^(row&7). FUSED RMSNorm+RoPE (z<2) / V blend (z=2).
// ---------------------------------------------------------------------------
__global__ __launch_bounds__(256) void gemm_qkv(
        const ushort_t* __restrict__ xb,
        const ushort_t* __restrict__ Wqb, const ushort_t* __restrict__ Wkb,
        const ushort_t* __restrict__ Wvb,
        const float* __restrict__ vi, const float* __restrict__ lam,
        ushort_t* __restrict__ qb, ushort_t* __restrict__ kb,
        ushort_t* __restrict__ vbt)
{
    const int z = blockIdx.z;
    const ushort_t* __restrict__ W = (z == 0) ? Wqb : (z == 1) ? Wkb : Wvb;
    const int row0 = blockIdx.y * 64;
    const int col0 = blockIdx.x * 128;

    __shared__ ushort_t As[2 * 64 * 64];     // 16 KB (2 buffers)
    __shared__ ushort_t Bs[2 * 128 * 64];    // 32 KB

    const int tid = threadIdx.x;
    const int wave = tid >> 6, lane = tid & 63;
    const int wm = wave >> 1, wn = wave & 1;
    const int l15 = lane & 15, quad = lane >> 4;
    const int srow  = tid >> 3;                     // staging row 0..31
    const int sslot = (tid & 7) ^ (srow & 7);       // pre-swizzled 16B slot

    floatx4 acc[2][4];
    #pragma unroll
    for (int i = 0; i < 2; ++i)
        #pragma unroll
        for (int j = 0; j < 4; ++j)
            acc[i][j] = (floatx4){0.f, 0.f, 0.f, 0.f};

    // stage tile at k-offset k0 into buffer p (6 gloads/wave)
    auto stageAB = [&](int k0, int p) {
        ushort_t* Ap = As + p * 4096;
        ushort_t* Bp = Bs + p * 8192;
        #pragma unroll
        for (int c = 0; c < 2; ++c)
            gload16(xb + (size_t)(row0 + c * 32 + srow) * D_MODEL + k0 + sslot * 8,
                    Ap + c * 2048 + tid * 8);
        #pragma unroll
        for (int c = 0; c < 4; ++c)
            gload16(W + (size_t)(col0 + c * 32 + srow) * D_MODEL + k0 + sslot * 8,
                    Bp + c * 2048 + tid * 8);
    };

    stageAB(0, 0);
    int cur = 0;
    for (int k0 = 0; k0 < D_MODEL; k0 += 64) {
        asm volatile("s_waitcnt vmcnt(0)" ::: "memory");   // cur's 6 loads (1 iter old)
        __builtin_amdgcn_s_barrier();
        const ushort_t* Ac = As + cur * 4096;
        const ushort_t* Bc = Bs + cur * 8192;
        short8 a[2][2], b[2][4];
        #pragma unroll
        for (int kh = 0; kh < 2; ++kh) {
            const int slot = ((kh * 4 + quad) ^ (l15 & 7)) << 3;  // ushort offs
            #pragma unroll
            for (int i = 0; i < 2; ++i)
                a[kh][i] = *(const short8*)(Ac + (32 * wm + i * 16 + l15) * 64 + slot);
            #pragma unroll
            for (int j = 0; j < 4; ++j)
                b[kh][j] = *(const short8*)(Bc + (64 * wn + j * 16 + l15) * 64 + slot);
        }
        __builtin_amdgcn_sched_barrier(0);    // ds_reads stay above
        if (k0 + 64 < D_MODEL) stageAB(k0 + 64, cur ^ 1);
        __builtin_amdgcn_sched_barrier(0);    // gload issue stays above MFMAs
        #pragma unroll
        for (int kh = 0; kh < 2; ++kh)
            #pragma unroll
            for (int i = 0; i < 2; ++i)
                #pragma unroll
                for (int j = 0; j < 4; ++j)
                    acc[i][j] = __builtin_amdgcn_mfma_f32_16x16x32_bf16(a[kh][i], b[kh][j], acc[i][j], 0, 0, 0);
        cur ^= 1;
    }

    if (z < 2) {
        ushort_t* __restrict__ o = (z == 0) ? qb : kb;
        const float oscale = (z == 0) ? 0.125f : 1.0f;   // fold 1/sqrt(hd) into q
        const int hbase = col0 + 64 * wn;
        const float eps = 1.1920929e-7f;
        const float fr = exp2f(-10.0f * (float)l15 / 15.0f);  // rotating-pair freq
        #pragma unroll
        for (int i = 0; i < 2; ++i)
            #pragma unroll
            for (int r = 0; r < 4; ++r) {
                const int t = row0 + 32 * wm + i * 16 + quad * 4 + r;
                float v0 = acc[i][0][r], v1 = acc[i][1][r];
                float v2 = acc[i][2][r], v3 = acc[i][3][r];
                float ss = v0 * v0 + v1 * v1 + v2 * v2 + v3 * v3;
                ss += __shfl_xor(ss, 1);
                ss += __shfl_xor(ss, 2);
                ss += __shfl_xor(ss, 4);
                ss += __shfl_xor(ss, 8);
                const float sc = rsqrtf(ss * (1.0f / 64.0f) + eps);
                v0 *= sc; v1 *= sc; v2 *= sc; v3 *= sc;
                const float th = (float)t * fr;
                const float cs = cosf(th), sn = sinf(th);
                const float y0 = v0 * cs + v2 * sn;   // shown-source rotary sign
                const float y2 = v2 * cs - v0 * sn;
                const size_t rb = (size_t)t * D_MODEL + hbase;
                o[rb +  0 + l15] = f2bf(y0 * oscale);
                o[rb + 16 + l15] = f2bf(v1 * oscale);
                o[rb + 32 + l15] = f2bf(y2 * oscale);
                o[rb + 48 + l15] = f2bf(v3 * oscale);
            }
    } else {
        const float l0 = lam[0], l1 = lam[1];
        #pragma unroll
        for (int i = 0; i < 2; ++i)
            #pragma unroll
            for (int j = 0; j < 4; ++j) {
                const int tb = row0 + 32 * wm + i * 16 + quad * 4;
                const int jj = col0 + 64 * wn + j * 16 + l15;
                float b0 = l0 * acc[i][j][0] + l1 * vi[(size_t)(tb + 0) * D_MODEL + jj];
                float b1 = l0 * acc[i][j][1] + l1 * vi[(size_t)(tb + 1) * D_MODEL + jj];
                float b2 = l0 * acc[i][j][2] + l1 * vi[(size_t)(tb + 2) * D_MODEL + jj];
                float b3 = l0 * acc[i][j][3] + l1 * vi[(size_t)(tb + 3) * D_MODEL + jj];
                uint2 u;
                u.x = pack2(b0, b1);
                u.y = pack2(b2, b3);
                *(uint2*)(vbt + (size_t)jj * T_SEQ + tb) = u;   // [d][t]
            }
    }
}

// ---------------------------------------------------------------------------
// Kernel 2: MFMA flash attention (UNCHANGED from round 8 for attribution):
// KV-split, fixed-max softmax, 2-phase dbuf K/V via global_load_lds,
// counted vmcnt(4) + raw s_barrier. Rebalanced split, makespan 14:
//   x in [ 0,28): 2-way chunks of qt = 27 - x/2      (sizes 8..14)
//   x in [28,40): 3-way chunks of qt = 28 + (x-28)/3 (sizes 9..11)
//   x in [40,54): direct qt = 53 - x                 (sizes 14..1, backfill)
// ---------------------------------------------------------------------------
__global__ __launch_bounds__(256) void attn(
        const ushort_t* __restrict__ qb, const ushort_t* __restrict__ kb,
        const ushort_t* __restrict__ vbt, ushort_t* __restrict__ yb,
        float* __restrict__ Opart, float* __restrict__ Lpart)
{
    const int h = blockIdx.x;
    const int x = blockIdx.y;
    int qt, ct_begin, ct_end, pidx;
    if (x < 28) {                       // 2-way, qt 27..14
        qt = 27 - (x >> 1);
        const int w = qt + 1;
        const int c0 = (w + 1) >> 1;
        if ((x & 1) == 0) { ct_begin = 0;  ct_end = c0; }
        else              { ct_begin = c0; ct_end = w;  }   // contains diag
        pidx = h * 40 + 12 + (qt - 14) * 2 + (x & 1);
    } else if (x < 40) {                // 3-way, qt 28..31
        const int xx = x - 28;
        qt = 28 + xx / 3;
        const int c = xx % 3;
        const int w = qt + 1;
        const int b0 = (w + 2) / 3;
        const int b1 = (2 * w + 2) / 3;
        ct_begin = (c == 0) ? 0  : (c == 1) ? b0 : b1;
        ct_end   = (c == 0) ? b0 : (c == 1) ? b1 : w;
        pidx = h * 40 + (qt - 28) * 3 + c;
    } else {                            // direct, qt 13..0
        qt = 53 - x;
        ct_begin = 0; ct_end = qt + 1;
        pidx = -1;
    }
    const int t0 = qt * 64;

    __shared__ ushort_t Ks[2 * 64 * 64];   // [s_local][d] linear, swizzled
    __shared__ ushort_t Vs[2 * 64 * 64];   // [d][s_local] linear, swizzled
    __shared__ ushort_t QPs[64 * LDK];     // Q tile, then reused for P

    const int tid = threadIdx.x;
    const int wave = tid >> 6, lane = tid & 63;
    const int l15 = lane & 15, quad = lane >> 4;
    const int r4 = tid >> 2, c4 = (tid & 3) * 16;
    const int srow  = tid >> 3;                   // staging row 0..31
    const int sslot = (tid & 7) ^ (srow & 7);     // pre-swizzled 16B slot
    const int bx = l15 & 7;

    // stage Q (64x64) once
    cp16(QPs + r4 * LDK + c4, qb + (size_t)(t0 + r4) * D_MODEL + h * HD + c4);
    __syncthreads();
    short8 qf[2];
    qf[0] = *(const short8*)(QPs + (16 * wave + l15) * LDK + 0  + quad * 8);
    qf[1] = *(const short8*)(QPs + (16 * wave + l15) * LDK + 32 + quad * 8);

    auto stageKV = [&](int kt, int p) {
        const int s0 = kt * 64;
        ushort_t* Kp = Ks + p * 4096;
        ushort_t* Vp = Vs + p * 4096;
        gload16(kb  + (size_t)(s0 + srow)      * D_MODEL + h * HD + sslot * 8, Kp + tid * 8);
        gload16(kb  + (size_t)(s0 + 32 + srow) * D_MODEL + h * HD + sslot * 8, Kp + 2048 + tid * 8);
        gload16(vbt + (size_t)(h * HD + srow)      * T_SEQ + s0 + sslot * 8,   Vp + tid * 8);
        gload16(vbt + (size_t)(h * HD + 32 + srow) * T_SEQ + s0 + sslot * 8,   Vp + 2048 + tid * 8);
    };

    float l_acc[4];
    floatx4 O[4];
    #pragma unroll
    for (int r = 0; r < 4; ++r) l_acc[r] = 0.0f;
    #pragma unroll
    for (int d = 0; d < 4; ++d) O[d] = (floatx4){0.f, 0.f, 0.f, 0.f};

    stageKV(ct_begin, 0);
    int cur = 0;
    for (int kt = ct_begin; kt < ct_end; ++kt) {
        const bool haveNext = (kt + 1 < ct_end);
        if (haveNext) {
            stageKV(kt + 1, cur ^ 1);
            asm volatile("s_waitcnt vmcnt(4)" ::: "memory");
        } else {
            asm volatile("s_waitcnt vmcnt(0)" ::: "memory");
        }
        __builtin_amdgcn_s_barrier();

        const ushort_t* Kc = Ks + cur * 4096;
        const ushort_t* Vc = Vs + cur * 4096;

        floatx4 sa[4];
        #pragma unroll
        for (int ct = 0; ct < 4; ++ct) {
            const ushort_t* krow = Kc + (ct * 16 + l15) * 64;
            short8 b0 = *(const short8*)(krow + ((quad ^ bx) << 3));
            short8 b1 = *(const short8*)(krow + (((quad + 4) ^ bx) << 3));
            floatx4 t4 = (floatx4){0.f, 0.f, 0.f, 0.f};
            t4 = __builtin_amdgcn_mfma_f32_16x16x32_bf16(qf[0], b0, t4, 0, 0, 0);
            t4 = __builtin_amdgcn_mfma_f32_16x16x32_bf16(qf[1], b1, t4, 0, 0, 0);
            sa[ct] = t4;
        }
        if (kt == qt) {   // causal mask on the diagonal tile
            #pragma unroll
            for (int ct = 0; ct < 4; ++ct)
                #pragma unroll
                for (int r = 0; r < 4; ++r) {
                    int trow = 16 * wave + quad * 4 + r;
                    int scol = ct * 16 + l15;
                    if (scol > trow) sa[ct][r] = -1e30f;
                }
        }
        // fixed-max softmax: p = exp(s - 8), per-lane l accumulation only
        float p[4][4];
        #pragma unroll
        for (int ct = 0; ct < 4; ++ct)
            #pragma unroll
            for (int r = 0; r < 4; ++r) {
                p[ct][r] = __expf(sa[ct][r] - 8.0f);
                l_acc[r] += p[ct][r];
            }

        // P -> LDS (wave-private 16-row stripe; no barrier needed)
        #pragma unroll
        for (int ct = 0; ct < 4; ++ct)
            #pragma unroll
            for (int r = 0; r < 4; ++r)
                QPs[(16 * wave + quad * 4 + r) * LDK + ct * 16 + l15] = f2bf(p[ct][r]);

        short8 pa0 = *(const short8*)(QPs + (16 * wave + l15) * LDK + 0  + quad * 8);
        short8 pa1 = *(const short8*)(QPs + (16 * wave + l15) * LDK + 32 + quad * 8);
        #pragma unroll
        for (int dt = 0; dt < 4; ++dt) {
            const ushort_t* vrow = Vc + (dt * 16 + l15) * 64;
            short8 vb0 = *(const short8*)(vrow + ((quad ^ bx) << 3));
            short8 vb1 = *(const short8*)(vrow + (((quad + 4) ^ bx) << 3));
            O[dt] = __builtin_amdgcn_mfma_f32_16x16x32_bf16(pa0, vb0, O[dt], 0, 0, 0);
            O[dt] = __builtin_amdgcn_mfma_f32_16x16x32_bf16(pa1, vb1, O[dt], 0, 0, 0);
        }

        asm volatile("" ::: "memory");
        __builtin_amdgcn_s_barrier();   // protect buf before next overwrite
        cur ^= 1;
    }

    // one-time row-sum reduce across the 16 col-lanes
    float l_run[4];
    #pragma unroll
    for (int r = 0; r < 4; ++r) {
        float s = l_acc[r];
        s += __shfl_xor(s, 1);
        s += __shfl_xor(s, 2);
        s += __shfl_xor(s, 4);
        s += __shfl_xor(s, 8);
        l_run[r] = s;
    }

    if (pidx < 0) {
        // direct: normalize and write bf16
        #pragma unroll
        for (int r = 0; r < 4; ++r) {
            const float inv_l = 1.0f / l_run[r];
            const int t = t0 + 16 * wave + quad * 4 + r;
            #pragma unroll
            for (int dt = 0; dt < 4; ++dt)
                yb[(size_t)t * D_MODEL + h * HD + dt * 16 + l15] = f2bf(O[dt][r] * inv_l);
        }
    } else {
        // partial: unnormalized fp32 O + per-row l (fixed max => no m needed)
        float* __restrict__ Op = Opart + (size_t)pidx * 4096;
        #pragma unroll
        for (int r = 0; r < 4; ++r) {
            const int row = 16 * wave + quad * 4 + r;
            #pragma unroll
            for (int dt = 0; dt < 4; ++dt)
                Op[row * 64 + dt * 16 + l15] = O[dt][r];
            if (l15 == 0) Lpart[(size_t)pidx * 64 + row] = l_run[r];
        }
    }
}

// ---------------------------------------------------------------------------
// Kernel 2b: combine the 2 or 3 KV-chunk partials for qt in [14,32).
// Fixed max on all chunks => combined = (sum O_c) / (sum l_c).
// grid = (16 h, 18 qt-14). Thread = one (row, 16-col segment).
// ---------------------------------------------------------------------------
__global__ __launch_bounds__(256) void attn_combine(
        const float* __restrict__ Opart, const float* __restrict__ Lpart,
        ushort_t* __restrict__ yb)
{
    const int h  = blockIdx.x;
    const int qt = 14 + (int)blockIdx.y;   // 14..31
    const int tid = threadIdx.x;
    const int row  = tid >> 2;           // 0..63
    const int dseg = (tid & 3) * 16;     // 0/16/32/48
    int s0, nc;
    if (qt >= 28) { s0 = (qt - 28) * 3;        nc = 3; }
    else          { s0 = 12 + (qt - 14) * 2;   nc = 2; }
    const int p0 = h * 40 + s0;

    float accv[16];
    #pragma unroll
    for (int e = 0; e < 16; ++e) accv[e] = 0.0f;
    float lsum = 0.0f;
    for (int c = 0; c < nc; ++c) {
        const float* Op = Opart + (size_t)(p0 + c) * 4096 + row * 64 + dseg;
        lsum += Lpart[(size_t)(p0 + c) * 64 + row];
        #pragma unroll
        for (int g = 0; g < 4; ++g) {
            float4 a = ((const float4*)Op)[g];
            accv[g * 4 + 0] += a.x;
            accv[g * 4 + 1] += a.y;
            accv[g * 4 + 2] += a.z;
            accv[g * 4 + 3] += a.w;
        }
    }
    const float inv = 1.0f / lsum;

    uint_t u[8];
    #pragma unroll
    for (int g = 0; g < 4; ++g) {
        u[g * 2 + 0] = pack2(accv[g * 4 + 0] * inv, accv[g * 4 + 1] * inv);
        u[g * 2 + 1] = pack2(accv[g * 4 + 2] * inv, accv[g * 4 + 3] * inv);
    }
    const int t = qt * 64 + row;
    uint4* dst = (uint4*)(yb + (size_t)t * D_MODEL + h * HD + dseg);
    dst[0] = make_uint4(u[0], u[1], u[2], u[3]);
    dst[1] = make_uint4(u[4], u[5], u[6], u[7]);
}

// ---------------------------------------------------------------------------
// Kernel 3: output projection, BM=64 BN=128 BK=64, grid (8,32) = 256 blocks
// = 1/CU. Same DS-READ-FIRST 2-phase dbuf structure as gemm_qkv. fp32 out.
// ---------------------------------------------------------------------------
__global__ __launch_bounds__(256) void gemm_proj(
        const ushort_t* __restrict__ yb, const ushort_t* __restrict__ Wpb,
        float* __restrict__ out)
{
    const int row0 = blockIdx.y * 64;
    const int col0 = blockIdx.x * 128;

    __shared__ ushort_t As[2 * 64 * 64];
    __shared__ ushort_t Bs[2 * 128 * 64];

    const int tid = threadIdx.x;
    const int wave = tid >> 6, lane = tid & 63;
    const int wm = wave >> 1, wn = wave & 1;
    const int l15 = lane & 15, quad = lane >> 4;
    const int srow  = tid >> 3;
    const int sslot = (tid & 7) ^ (srow & 7);

    floatx4 acc[2][4];
    #pragma unroll
    for (int i = 0; i < 2; ++i)
        #pragma unroll
        for (int j = 0; j < 4; ++j)
            acc[i][j] = (floatx4){0.f, 0.f, 0.f, 0.f};

    auto stageAB = [&](int k0, int p) {
        ushort_t* Ap = As + p * 4096;
        ushort_t* Bp = Bs + p * 8192;
        #pragma unroll
        for (int c = 0; c < 2; ++c)
            gload16(yb + (size_t)(row0 + c * 32 + srow) * D_MODEL + k0 + sslot * 8,
                    Ap + c * 2048 + tid * 8);
        #pragma unroll
        for (int c = 0; c < 4; ++c)
            gload16(Wpb + (size_t)(col0 + c * 32 + srow) * D_MODEL + k0 + sslot * 8,
                    Bp + c * 2048 + tid * 8);
    };

    stageAB(0, 0);
    int cur = 0;
    for (int k0 = 0; k0 < D_MODEL; k0 += 64) {
        asm volatile("s_waitcnt vmcnt(0)" ::: "memory");
        __builtin_amdgcn_s_barrier();
        const ushort_t* Ac = As + cur * 4096;
        const ushort_t* Bc = Bs + cur * 8192;
        short8 a[2][2], b[2][4];
        #pragma unroll
        for (int kh = 0; kh < 2; ++kh) {
            const int slot = ((kh * 4 + quad) ^ (l15 & 7)) << 3;
            #pragma unroll
            for (int i = 0; i < 2; ++i)
                a[kh][i] = *(const short8*)(Ac + (32 * wm + i * 16 + l15) * 64 + slot);
            #pragma unroll
            for (int j = 0; j < 4; ++j)
                b[kh][j] = *(const short8*)(Bc + (64 * wn + j * 16 + l15) * 64 + slot);
        }
        __builtin_amdgcn_sched_barrier(0);
        if (k0 + 64 < D_MODEL) stageAB(k0 + 64, cur ^ 1);
        __builtin_amdgcn_sched_barrier(0);
        #pragma unroll
        for (int kh = 0; kh < 2; ++kh)
            #pragma unroll
            for (int i = 0; i < 2; ++i)
                #pragma unroll
                for (int j = 0; j < 4; ++j)
                    acc[i][j] = __builtin_amdgcn_mfma_f32_16x16x32_bf16(a[kh][i], b[kh][j], acc[i][j], 0, 0, 0);
        cur ^= 1;
    }

    #pragma unroll
    for (int i = 0; i < 2; ++i)
        #pragma unroll
        for (int j = 0; j < 4; ++j) {
            const int t = row0 + 32 * wm + i * 16 + quad * 4;
            const int jj = col0 + 64 * wn + j * 16 + l15;
            #pragma unroll
            for (int r = 0; r < 4; ++r)
                out[(size_t)(t + r) * D_MODEL + jj] = acc[i][j][r];
        }
}

// ---------------------------------------------------------------------------
extern "C" void kernel_launch(void* const* d_in, const int* in_sizes, int n_in,
                              void* d_out, int out_size, void* d_ws, size_t ws_size,
                              hipStream_t stream) {
    (void)in_sizes; (void)n_in; (void)out_size; (void)ws_size;
    const float* x   = (const float*)d_in[0];
    const float* vi  = (const float*)d_in[1];
    const float* Wq  = (const float*)d_in[2];
    const float* Wk  = (const float*)d_in[3];
    const float* Wv  = (const float*)d_in[4];
    const float* Wp  = (const float*)d_in[5];
    const float* lam = (const float*)d_in[6];

    char* base = (char*)d_ws;                                  // 28 MiB used
    ushort_t* xb  = (ushort_t*)(base);                         // [ 0, 4) MiB (dead after gemm_qkv)
    ushort_t* wqb = (ushort_t*)(base + (size_t)4  * 1048576);  // [ 4, 6)  (dead after gemm_qkv)
    ushort_t* wkb = (ushort_t*)(base + (size_t)6  * 1048576);  // [ 6, 8)  (dead after gemm_qkv)
    ushort_t* wvb = (ushort_t*)(base + (size_t)8  * 1048576);  // [ 8,10)  (dead after gemm_qkv)
    ushort_t* wpb = (ushort_t*)(base + (size_t)10 * 1048576);  // [10,12)  (live until gemm_proj)
    ushort_t* qb  = (ushort_t*)(base + (size_t)12 * 1048576);  // [12,16)
    ushort_t* kb  = (ushort_t*)(base + (size_t)16 * 1048576);  // [16,20)
    ushort_t* vbt = (ushort_t*)(base + (size_t)20 * 1048576);  // [20,24)  [d][t]
    ushort_t* yb  = (ushort_t*)(base + (size_t)24 * 1048576);  // [24,28)
    // attn partials: Opart = 640 * 16 KB = 10 MiB in dead [0,10) region;
    // Lpart = 640 * 64 * 4B = 160 KB in d_out (scratch until gemm_proj).
    float* Opart  = (float*)(base);
    float* Lpart  = (float*)d_out;
    float* out = (float*)d_out;

    to_bf16<<<dim3(786432 / 256), 256, 0, stream>>>(x, Wq, Wk, Wv, Wp, xb, wqb, wkb, wvb, wpb);
    gemm_qkv<<<dim3(8, 32, 3), 256, 0, stream>>>(xb, wqb, wkb, wvb, vi, lam, qb, kb, vbt);
    attn<<<dim3(16, 54), 256, 0, stream>>>(qb, kb, vbt, yb, Opart, Lpart);
    attn_combine<<<dim3(16, 18), 256, 0, stream>>>(Opart, Lpart, yb);
    gemm_proj<<<dim3(8, 32), 256, 0, stream>>>(yb, wpb, out);
}

// Round 10
// 142.473 us; speedup vs baseline: 1.0834x; 1.0118x over previous
//
#include <hip/hip_runtime.h>
#include <math.h>

#define T_SEQ 2048
#define D_MODEL 1024
#define NH 16
#define HD 64

typedef unsigned short ushort_t;
typedef unsigned int uint_t;
typedef short short8 __attribute__((ext_vector_type(8)));
typedef float floatx4 __attribute__((ext_vector_type(4)));

// ---- bf16 helpers (RNE) ----
__device__ __forceinline__ ushort_t f2bf(float f) {
    uint_t u = __float_as_uint(f);
    u += 0x7FFFu + ((u >> 16) & 1u);
    return (ushort_t)(u >> 16);
}
__device__ __forceinline__ uint_t pack2(float a, float b) {
    return (uint_t)f2bf(a) | ((uint_t)f2bf(b) << 16);
}
// async global -> LDS, 16B per lane (wave-uniform LDS base + lane*16)
__device__ __forceinline__ void gload16(const ushort_t* g, ushort_t* l) {
    __builtin_amdgcn_global_load_lds(
        (const __attribute__((address_space(1))) void*)g,
        (__attribute__((address_space(3))) void*)l, 16, 0, 0);
}

// ---------------------------------------------------------------------------
// Kernel 0: one-time fp32 -> bf16 convert of x, Wq, Wk, Wv, Wp.
// ---------------------------------------------------------------------------
__global__ __launch_bounds__(256) void to_bf16(
        const float* __restrict__ x,  const float* __restrict__ wq,
        const float* __restrict__ wk, const float* __restrict__ wv,
        const float* __restrict__ wp,
        ushort_t* __restrict__ xb,  ushort_t* __restrict__ wqb,
        ushort_t* __restrict__ wkb, ushort_t* __restrict__ wvb,
        ushort_t* __restrict__ wpb)
{
    size_t i = (size_t)blockIdx.x * 256 + threadIdx.x;
    const float* src; ushort_t* dst; size_t off;
    if (i < 262144)      { src = x;  dst = xb;  off = i; }
    else if (i < 393216) { src = wq; dst = wqb; off = i - 262144; }
    else if (i < 524288) { src = wk; dst = wkb; off = i - 393216; }
    else if (i < 655360) { src = wv; dst = wvb; off = i - 524288; }
    else                 { src = wp; dst = wpb; off = i - 655360; }
    float4 f0 = ((const float4*)src)[off * 2];
    float4 f1 = ((const float4*)src)[off * 2 + 1];
    uint4 u;
    u.x = pack2(f0.x, f0.y); u.y = pack2(f0.z, f0.w);
    u.z = pack2(f1.x, f1.y); u.w = pack2(f1.z, f1.w);
    ((uint4*)dst)[off] = u;
}

// ---------------------------------------------------------------------------
// Kernel 1: QKV GEMM (bf16 MFMA), BM=64 BN=128 BK=64, grid (8,32,3) = 768
// blocks = 3/CU. 2-phase dbuf, ds-read-first, ONE barrier/iter (R9 struct).
// XOR-swizzle: writer fetches logical slot (tid&7)^(row&7); reader reads
// phys slot (kh*4+quad)^(row&7). FUSED RMSNorm+RoPE (z<2) / V blend (z=2).
// ---------------------------------------------------------------------------
__global__ __launch_bounds__(256) void gemm_qkv(
        const ushort_t* __restrict__ xb,
        const ushort_t* __restrict__ Wqb, const ushort_t* __restrict__ Wkb,
        const ushort_t* __restrict__ Wvb,
        const float* __restrict__ vi, const float* __restrict__ lam,
        ushort_t* __restrict__ qb, ushort_t* __restrict__ kb,
        ushort_t* __restrict__ vbt)
{
    const int z = blockIdx.z;
    const ushort_t* __restrict__ W = (z == 0) ? Wqb : (z == 1) ? Wkb : Wvb;
    const int row0 = blockIdx.y * 64;
    const int col0 = blockIdx.x * 128;

    __shared__ ushort_t As[2 * 64 * 64];     // 16 KB (2 buffers)
    __shared__ ushort_t Bs[2 * 128 * 64];    // 32 KB

    const int tid = threadIdx.x;
    const int wave = tid >> 6, lane = tid & 63;
    const int wm = wave >> 1, wn = wave & 1;
    const int l15 = lane & 15, quad = lane >> 4;
    const int srow  = tid >> 3;                     // staging row 0..31
    const int sslot = (tid & 7) ^ (srow & 7);       // pre-swizzled 16B slot

    floatx4 acc[2][4];
    #pragma unroll
    for (int i = 0; i < 2; ++i)
        #pragma unroll
        for (int j = 0; j < 4; ++j)
            acc[i][j] = (floatx4){0.f, 0.f, 0.f, 0.f};

    // stage tile at k-offset k0 into buffer p (6 gloads/wave)
    auto stageAB = [&](int k0, int p) {
        ushort_t* Ap = As + p * 4096;
        ushort_t* Bp = Bs + p * 8192;
        #pragma unroll
        for (int c = 0; c < 2; ++c)
            gload16(xb + (size_t)(row0 + c * 32 + srow) * D_MODEL + k0 + sslot * 8,
                    Ap + c * 2048 + tid * 8);
        #pragma unroll
        for (int c = 0; c < 4; ++c)
            gload16(W + (size_t)(col0 + c * 32 + srow) * D_MODEL + k0 + sslot * 8,
                    Bp + c * 2048 + tid * 8);
    };

    stageAB(0, 0);
    int cur = 0;
    for (int k0 = 0; k0 < D_MODEL; k0 += 64) {
        asm volatile("s_waitcnt vmcnt(0)" ::: "memory");   // cur's 6 loads (1 iter old)
        __builtin_amdgcn_s_barrier();
        const ushort_t* Ac = As + cur * 4096;
        const ushort_t* Bc = Bs + cur * 8192;
        short8 a[2][2], b[2][4];
        #pragma unroll
        for (int kh = 0; kh < 2; ++kh) {
            const int slot = ((kh * 4 + quad) ^ (l15 & 7)) << 3;  // ushort offs
            #pragma unroll
            for (int i = 0; i < 2; ++i)
                a[kh][i] = *(const short8*)(Ac + (32 * wm + i * 16 + l15) * 64 + slot);
            #pragma unroll
            for (int j = 0; j < 4; ++j)
                b[kh][j] = *(const short8*)(Bc + (64 * wn + j * 16 + l15) * 64 + slot);
        }
        __builtin_amdgcn_sched_barrier(0);    // ds_reads stay above
        if (k0 + 64 < D_MODEL) stageAB(k0 + 64, cur ^ 1);
        __builtin_amdgcn_sched_barrier(0);    // gload issue stays above MFMAs
        #pragma unroll
        for (int kh = 0; kh < 2; ++kh)
            #pragma unroll
            for (int i = 0; i < 2; ++i)
                #pragma unroll
                for (int j = 0; j < 4; ++j)
                    acc[i][j] = __builtin_amdgcn_mfma_f32_16x16x32_bf16(a[kh][i], b[kh][j], acc[i][j], 0, 0, 0);
        cur ^= 1;
    }

    if (z < 2) {
        ushort_t* __restrict__ o = (z == 0) ? qb : kb;
        const float oscale = (z == 0) ? 0.125f : 1.0f;   // fold 1/sqrt(hd) into q
        const int hbase = col0 + 64 * wn;
        const float eps = 1.1920929e-7f;
        const float fr = exp2f(-10.0f * (float)l15 / 15.0f);  // rotating-pair freq
        #pragma unroll
        for (int i = 0; i < 2; ++i)
            #pragma unroll
            for (int r = 0; r < 4; ++r) {
                const int t = row0 + 32 * wm + i * 16 + quad * 4 + r;
                float v0 = acc[i][0][r], v1 = acc[i][1][r];
                float v2 = acc[i][2][r], v3 = acc[i][3][r];
                float ss = v0 * v0 + v1 * v1 + v2 * v2 + v3 * v3;
                ss += __shfl_xor(ss, 1);
                ss += __shfl_xor(ss, 2);
                ss += __shfl_xor(ss, 4);
                ss += __shfl_xor(ss, 8);
                const float sc = rsqrtf(ss * (1.0f / 64.0f) + eps);
                v0 *= sc; v1 *= sc; v2 *= sc; v3 *= sc;
                const float th = (float)t * fr;
                const float cs = cosf(th), sn = sinf(th);
                const float y0 = v0 * cs + v2 * sn;   // shown-source rotary sign
                const float y2 = v2 * cs - v0 * sn;
                const size_t rb = (size_t)t * D_MODEL + hbase;
                o[rb +  0 + l15] = f2bf(y0 * oscale);
                o[rb + 16 + l15] = f2bf(v1 * oscale);
                o[rb + 32 + l15] = f2bf(y2 * oscale);
                o[rb + 48 + l15] = f2bf(v3 * oscale);
            }
    } else {
        const float l0 = lam[0], l1 = lam[1];
        #pragma unroll
        for (int i = 0; i < 2; ++i)
            #pragma unroll
            for (int j = 0; j < 4; ++j) {
                const int tb = row0 + 32 * wm + i * 16 + quad * 4;
                const int jj = col0 + 64 * wn + j * 16 + l15;
                float b0 = l0 * acc[i][j][0] + l1 * vi[(size_t)(tb + 0) * D_MODEL + jj];
                float b1 = l0 * acc[i][j][1] + l1 * vi[(size_t)(tb + 1) * D_MODEL + jj];
                float b2 = l0 * acc[i][j][2] + l1 * vi[(size_t)(tb + 2) * D_MODEL + jj];
                float b3 = l0 * acc[i][j][3] + l1 * vi[(size_t)(tb + 3) * D_MODEL + jj];
                uint2 u;
                u.x = pack2(b0, b1);
                u.y = pack2(b2, b3);
                *(uint2*)(vbt + (size_t)jj * T_SEQ + tb) = u;   // [d][t]
            }
    }
}

// ---------------------------------------------------------------------------
// Kernel 2: MFMA flash attention. Changes this round:
//  - QPs shrunk [64][72] -> [64][64] with XOR slot-swizzle (slot ^= row&7)
//    on Q-stage/P-write/frag-read => LDS total exactly 40 KB -> 4 blocks/CU
//    (was 44 KB -> 3). Swizzle aliasing is 2-way = free.
//  - ONE barrier per KV-tile: stage issued AFTER top barrier (all waves
//    finished reading buf cur^1 at iter kt-1 before kt's barrier).
//  - s_setprio(1) around QK and PV MFMA clusters (T5; +4-7% attn in m191).
// Fixed-max softmax (|s|<=8 provable), rebalanced KV-split (makespan 14):
//   x in [ 0,28): 2-way chunks of qt = 27 - x/2      (sizes 8..14)
//   x in [28,40): 3-way chunks of qt = 28 + (x-28)/3 (sizes 9..11)
//   x in [40,54): direct qt = 53 - x                 (sizes 14..1, backfill)
// ---------------------------------------------------------------------------
__global__ __launch_bounds__(256) void attn(
        const ushort_t* __restrict__ qb, const ushort_t* __restrict__ kb,
        const ushort_t* __restrict__ vbt, ushort_t* __restrict__ yb,
        float* __restrict__ Opart, float* __restrict__ Lpart)
{
    const int h = blockIdx.x;
    const int x = blockIdx.y;
    int qt, ct_begin, ct_end, pidx;
    if (x < 28) {                       // 2-way, qt 27..14
        qt = 27 - (x >> 1);
        const int w = qt + 1;
        const int c0 = (w + 1) >> 1;
        if ((x & 1) == 0) { ct_begin = 0;  ct_end = c0; }
        else              { ct_begin = c0; ct_end = w;  }   // contains diag
        pidx = h * 40 + 12 + (qt - 14) * 2 + (x & 1);
    } else if (x < 40) {                // 3-way, qt 28..31
        const int xx = x - 28;
        qt = 28 + xx / 3;
        const int c = xx % 3;
        const int w = qt + 1;
        const int b0 = (w + 2) / 3;
        const int b1 = (2 * w + 2) / 3;
        ct_begin = (c == 0) ? 0  : (c == 1) ? b0 : b1;
        ct_end   = (c == 0) ? b0 : (c == 1) ? b1 : w;
        pidx = h * 40 + (qt - 28) * 3 + c;
    } else {                            // direct, qt 13..0
        qt = 53 - x;
        ct_begin = 0; ct_end = qt + 1;
        pidx = -1;
    }
    const int t0 = qt * 64;

    __shared__ ushort_t Ks[2 * 64 * 64];   // [s_local][d] linear, swizzled (16 KB)
    __shared__ ushort_t Vs[2 * 64 * 64];   // [d][s_local] linear, swizzled (16 KB)
    __shared__ ushort_t QPs[64 * 64];      // Q then P, XOR slot-swizzled (8 KB)

    const int tid = threadIdx.x;
    const int wave = tid >> 6, lane = tid & 63;
    const int l15 = lane & 15, quad = lane >> 4;
    const int srow  = tid >> 3;                   // staging row 0..31
    const int sslot = (tid & 7) ^ (srow & 7);     // pre-swizzled 16B slot
    const int bx = l15 & 7;

    // stage Q (64x64) once, swizzled: slot ^= row&7
    {
        const int r4 = tid >> 2, c4 = (tid & 3) * 16;
        const ushort_t* src = qb + (size_t)(t0 + r4) * D_MODEL + h * HD + c4;
        uint4 A = ((const uint4*)src)[0];
        uint4 B = ((const uint4*)src)[1];
        const int rs = r4 & 7;
        const int s0 = (c4 >> 3) ^ rs;        // c4>>3 is even
        const int s1 = ((c4 >> 3) + 1) ^ rs;
        *(uint4*)(QPs + r4 * 64 + s0 * 8) = A;
        *(uint4*)(QPs + r4 * 64 + s1 * 8) = B;
    }
    __syncthreads();
    short8 qf[2];
    qf[0] = *(const short8*)(QPs + (16 * wave + l15) * 64 + ((quad ^ bx) << 3));
    qf[1] = *(const short8*)(QPs + (16 * wave + l15) * 64 + (((quad + 4) ^ bx) << 3));

    auto stageKV = [&](int kt, int p) {
        const int s0 = kt * 64;
        ushort_t* Kp = Ks + p * 4096;
        ushort_t* Vp = Vs + p * 4096;
        gload16(kb  + (size_t)(s0 + srow)      * D_MODEL + h * HD + sslot * 8, Kp + tid * 8);
        gload16(kb  + (size_t)(s0 + 32 + srow) * D_MODEL + h * HD + sslot * 8, Kp + 2048 + tid * 8);
        gload16(vbt + (size_t)(h * HD + srow)      * T_SEQ + s0 + sslot * 8,   Vp + tid * 8);
        gload16(vbt + (size_t)(h * HD + 32 + srow) * T_SEQ + s0 + sslot * 8,   Vp + 2048 + tid * 8);
    };

    float l_acc[4];
    floatx4 O[4];
    #pragma unroll
    for (int r = 0; r < 4; ++r) l_acc[r] = 0.0f;
    #pragma unroll
    for (int d = 0; d < 4; ++d) O[d] = (floatx4){0.f, 0.f, 0.f, 0.f};

    stageKV(ct_begin, 0);
    int cur = 0;
    for (int kt = ct_begin; kt < ct_end; ++kt) {
        asm volatile("s_waitcnt vmcnt(0)" ::: "memory");  // cur's 4 loads done
        __builtin_amdgcn_s_barrier();                     // all waves past iter kt-1

        const ushort_t* Kc = Ks + cur * 4096;
        const ushort_t* Vc = Vs + cur * 4096;

        floatx4 sa[4];
        __builtin_amdgcn_s_setprio(1);
        #pragma unroll
        for (int ct = 0; ct < 4; ++ct) {
            const ushort_t* krow = Kc + (ct * 16 + l15) * 64;
            short8 b0 = *(const short8*)(krow + ((quad ^ bx) << 3));
            short8 b1 = *(const short8*)(krow + (((quad + 4) ^ bx) << 3));
            floatx4 t4 = (floatx4){0.f, 0.f, 0.f, 0.f};
            t4 = __builtin_amdgcn_mfma_f32_16x16x32_bf16(qf[0], b0, t4, 0, 0, 0);
            t4 = __builtin_amdgcn_mfma_f32_16x16x32_bf16(qf[1], b1, t4, 0, 0, 0);
            sa[ct] = t4;
        }
        __builtin_amdgcn_s_setprio(0);
        __builtin_amdgcn_sched_barrier(0);
        if (kt + 1 < ct_end) stageKV(kt + 1, cur ^ 1);    // safe: cur^1 last read
        __builtin_amdgcn_sched_barrier(0);                // at kt-1, fenced by barrier

        if (kt == qt) {   // causal mask on the diagonal tile
            #pragma unroll
            for (int ct = 0; ct < 4; ++ct)
                #pragma unroll
                for (int r = 0; r < 4; ++r) {
                    int trow = 16 * wave + quad * 4 + r;
                    int scol = ct * 16 + l15;
                    if (scol > trow) sa[ct][r] = -1e30f;
                }
        }
        // fixed-max softmax: p = exp(s - 8), per-lane l accumulation only
        float p[4][4];
        #pragma unroll
        for (int ct = 0; ct < 4; ++ct)
            #pragma unroll
            for (int r = 0; r < 4; ++r) {
                p[ct][r] = __expf(sa[ct][r] - 8.0f);
                l_acc[r] += p[ct][r];
            }

        // P -> LDS (wave-private 16-row stripe; swizzled; no barrier needed)
        #pragma unroll
        for (int ct = 0; ct < 4; ++ct)
            #pragma unroll
            for (int r = 0; r < 4; ++r) {
                const int row = 16 * wave + quad * 4 + r;
                const int ps = (ct * 2 + (l15 >> 3)) ^ (row & 7);
                QPs[row * 64 + ps * 8 + (l15 & 7)] = f2bf(p[ct][r]);
            }

        short8 pa0 = *(const short8*)(QPs + (16 * wave + l15) * 64 + ((quad ^ bx) << 3));
        short8 pa1 = *(const short8*)(QPs + (16 * wave + l15) * 64 + (((quad + 4) ^ bx) << 3));
        __builtin_amdgcn_s_setprio(1);
        #pragma unroll
        for (int dt = 0; dt < 4; ++dt) {
            const ushort_t* vrow = Vc + (dt * 16 + l15) * 64;
            short8 vb0 = *(const short8*)(vrow + ((quad ^ bx) << 3));
            short8 vb1 = *(const short8*)(vrow + (((quad + 4) ^ bx) << 3));
            O[dt] = __builtin_amdgcn_mfma_f32_16x16x32_bf16(pa0, vb0, O[dt], 0, 0, 0);
            O[dt] = __builtin_amdgcn_mfma_f32_16x16x32_bf16(pa1, vb1, O[dt], 0, 0, 0);
        }
        __builtin_amdgcn_s_setprio(0);
        cur ^= 1;
    }

    // one-time row-sum reduce across the 16 col-lanes
    float l_run[4];
    #pragma unroll
    for (int r = 0; r < 4; ++r) {
        float s = l_acc[r];
        s += __shfl_xor(s, 1);
        s += __shfl_xor(s, 2);
        s += __shfl_xor(s, 4);
        s += __shfl_xor(s, 8);
        l_run[r] = s;
    }

    if (pidx < 0) {
        // direct: normalize and write bf16
        #pragma unroll
        for (int r = 0; r < 4; ++r) {
            const float inv_l = 1.0f / l_run[r];
            const int t = t0 + 16 * wave + quad * 4 + r;
            #pragma unroll
            for (int dt = 0; dt < 4; ++dt)
                yb[(size_t)t * D_MODEL + h * HD + dt * 16 + l15] = f2bf(O[dt][r] * inv_l);
        }
    } else {
        // partial: unnormalized fp32 O + per-row l (fixed max => no m needed)
        float* __restrict__ Op = Opart + (size_t)pidx * 4096;
        #pragma unroll
        for (int r = 0; r < 4; ++r) {
            const int row = 16 * wave + quad * 4 + r;
            #pragma unroll
            for (int dt = 0; dt < 4; ++dt)
                Op[row * 64 + dt * 16 + l15] = O[dt][r];
            if (l15 == 0) Lpart[(size_t)pidx * 64 + row] = l_run[r];
        }
    }
}

// ---------------------------------------------------------------------------
// Kernel 2b: combine the 2 or 3 KV-chunk partials for qt in [14,32).
// Fixed max on all chunks => combined = (sum O_c) / (sum l_c).
// grid = (16 h, 18 qt-14). Thread = one (row, 16-col segment).
// ---------------------------------------------------------------------------
__global__ __launch_bounds__(256) void attn_combine(
        const float* __restrict__ Opart, const float* __restrict__ Lpart,
        ushort_t* __restrict__ yb)
{
    const int h  = blockIdx.x;
    const int qt = 14 + (int)blockIdx.y;   // 14..31
    const int tid = threadIdx.x;
    const int row  = tid >> 2;           // 0..63
    const int dseg = (tid & 3) * 16;     // 0/16/32/48
    int s0, nc;
    if (qt >= 28) { s0 = (qt - 28) * 3;        nc = 3; }
    else          { s0 = 12 + (qt - 14) * 2;   nc = 2; }
    const int p0 = h * 40 + s0;

    float accv[16];
    #pragma unroll
    for (int e = 0; e < 16; ++e) accv[e] = 0.0f;
    float lsum = 0.0f;
    for (int c = 0; c < nc; ++c) {
        const float* Op = Opart + (size_t)(p0 + c) * 4096 + row * 64 + dseg;
        lsum += Lpart[(size_t)(p0 + c) * 64 + row];
        #pragma unroll
        for (int g = 0; g < 4; ++g) {
            float4 a = ((const float4*)Op)[g];
            accv[g * 4 + 0] += a.x;
            accv[g * 4 + 1] += a.y;
            accv[g * 4 + 2] += a.z;
            accv[g * 4 + 3] += a.w;
        }
    }
    const float inv = 1.0f / lsum;

    uint_t u[8];
    #pragma unroll
    for (int g = 0; g < 4; ++g) {
        u[g * 2 + 0] = pack2(accv[g * 4 + 0] * inv, accv[g * 4 + 1] * inv);
        u[g * 2 + 1] = pack2(accv[g * 4 + 2] * inv, accv[g * 4 + 3] * inv);
    }
    const int t = qt * 64 + row;
    uint4* dst = (uint4*)(yb + (size_t)t * D_MODEL + h * HD + dseg);
    dst[0] = make_uint4(u[0], u[1], u[2], u[3]);
    dst[1] = make_uint4(u[4], u[5], u[6], u[7]);
}

// ---------------------------------------------------------------------------
// Kernel 3: output projection, BM=64 BN=128 BK=64, grid (8,32) = 256 blocks
// = 1/CU. Same ds-read-first 2-phase dbuf structure as gemm_qkv. fp32 out.
// ---------------------------------------------------------------------------
__global__ __launch_bounds__(256) void gemm_proj(
        const ushort_t* __restrict__ yb, const ushort_t* __restrict__ Wpb,
        float* __restrict__ out)
{
    const int row0 = blockIdx.y * 64;
    const int col0 = blockIdx.x * 128;

    __shared__ ushort_t As[2 * 64 * 64];
    __shared__ ushort_t Bs[2 * 128 * 64];

    const int tid = threadIdx.x;
    const int wave = tid >> 6, lane = tid & 63;
    const int wm = wave >> 1, wn = wave & 1;
    const int l15 = lane & 15, quad = lane >> 4;
    const int srow  = tid >> 3;
    const int sslot = (tid & 7) ^ (srow & 7);

    floatx4 acc[2][4];
    #pragma unroll
    for (int i = 0; i < 2; ++i)
        #pragma unroll
        for (int j = 0; j < 4; ++j)
            acc[i][j] = (floatx4){0.f, 0.f, 0.f, 0.f};

    auto stageAB = [&](int k0, int p) {
        ushort_t* Ap = As + p * 4096;
        ushort_t* Bp = Bs + p * 8192;
        #pragma unroll
        for (int c = 0; c < 2; ++c)
            gload16(yb + (size_t)(row0 + c * 32 + srow) * D_MODEL + k0 + sslot * 8,
                    Ap + c * 2048 + tid * 8);
        #pragma unroll
        for (int c = 0; c < 4; ++c)
            gload16(Wpb + (size_t)(col0 + c * 32 + srow) * D_MODEL + k0 + sslot * 8,
                    Bp + c * 2048 + tid * 8);
    };

    stageAB(0, 0);
    int cur = 0;
    for (int k0 = 0; k0 < D_MODEL; k0 += 64) {
        asm volatile("s_waitcnt vmcnt(0)" ::: "memory");
        __builtin_amdgcn_s_barrier();
        const ushort_t* Ac = As + cur * 4096;
        const ushort_t* Bc = Bs + cur * 8192;
        short8 a[2][2], b[2][4];
        #pragma unroll
        for (int kh = 0; kh < 2; ++kh) {
            const int slot = ((kh * 4 + quad) ^ (l15 & 7)) << 3;
            #pragma unroll
            for (int i = 0; i < 2; ++i)
                a[kh][i] = *(const short8*)(Ac + (32 * wm + i * 16 + l15) * 64 + slot);
            #pragma unroll
            for (int j = 0; j < 4; ++j)
                b[kh][j] = *(const short8*)(Bc + (64 * wn + j * 16 + l15) * 64 + slot);
        }
        __builtin_amdgcn_sched_barrier(0);
        if (k0 + 64 < D_MODEL) stageAB(k0 + 64, cur ^ 1);
        __builtin_amdgcn_sched_barrier(0);
        #pragma unroll
        for (int kh = 0; kh < 2; ++kh)
            #pragma unroll
            for (int i = 0; i < 2; ++i)
                #pragma unroll
                for (int j = 0; j < 4; ++j)
                    acc[i][j] = __builtin_amdgcn_mfma_f32_16x16x32_bf16(a[kh][i], b[kh][j], acc[i][j], 0, 0, 0);
        cur ^= 1;
    }

    #pragma unroll
    for (int i = 0; i < 2; ++i)
        #pragma unroll
        for (int j = 0; j < 4; ++j) {
            const int t = row0 + 32 * wm + i * 16 + quad * 4;
            const int jj = col0 + 64 * wn + j * 16 + l15;
            #pragma unroll
            for (int r = 0; r < 4; ++r)
                out[(size_t)(t + r) * D_MODEL + jj] = acc[i][j][r];
        }
}

// ---------------------------------------------------------------------------
extern "C" void kernel_launch(void* const* d_in, const int* in_sizes, int n_in,
                              void* d_out, int out_size, void* d_ws, size_t ws_size,
                              hipStream_t stream) {
    (void)in_sizes; (void)n_in; (void)out_size; (void)ws_size;
    const float* x   = (const float*)d_in[0];
    const float* vi  = (const float*)d_in[1];
    const float* Wq  = (const float*)d_in[2];
    const float* Wk  = (const float*)d_in[3];
    const float* Wv  = (const float*)d_in[4];
    const float* Wp  = (const float*)d_in[5];
    const float* lam = (const float*)d_in[6];

    char* base = (char*)d_ws;                                  // 28 MiB used
    ushort_t* xb  = (ushort_t*)(base);                         // [ 0, 4) MiB (dead after gemm_qkv)
    ushort_t* wqb = (ushort_t*)(base + (size_t)4  * 1048576);  // [ 4, 6)  (dead after gemm_qkv)
    ushort_t* wkb = (ushort_t*)(base + (size_t)6  * 1048576);  // [ 6, 8)  (dead after gemm_qkv)
    ushort_t* wvb = (ushort_t*)(base + (size_t)8  * 1048576);  // [ 8,10)  (dead after gemm_qkv)
    ushort_t* wpb = (ushort_t*)(base + (size_t)10 * 1048576);  // [10,12)  (live until gemm_proj)
    ushort_t* qb  = (ushort_t*)(base + (size_t)12 * 1048576);  // [12,16)
    ushort_t* kb  = (ushort_t*)(base + (size_t)16 * 1048576);  // [16,20)
    ushort_t* vbt = (ushort_t*)(base + (size_t)20 * 1048576);  // [20,24)  [d][t]
    ushort_t* yb  = (ushort_t*)(base + (size_t)24 * 1048576);  // [24,28)
    // attn partials: Opart = 640 * 16 KB = 10 MiB in dead [0,10) region;
    // Lpart = 640 * 64 * 4B = 160 KB in d_out (scratch until gemm_proj).
    float* Opart  = (float*)(base);
    float* Lpart  = (float*)d_out;
    float* out = (float*)d_out;

    to_bf16<<<dim3(786432 / 256), 256, 0, stream>>>(x, Wq, Wk, Wv, Wp, xb, wqb, wkb, wvb, wpb);
    gemm_qkv<<<dim3(8, 32, 3), 256, 0, stream>>>(xb, wqb, wkb, wvb, vi, lam, qb, kb, vbt);
    attn<<<dim3(16, 54), 256, 0, stream>>>(qb, kb, vbt, yb, Opart, Lpart);
    attn_combine<<<dim3(16, 18), 256, 0, stream>>>(Opart, Lpart, yb);
    gemm_proj<<<dim3(8, 32), 256, 0, stream>>>(yb, wpb, out);
}

// Round 11
// 139.988 us; speedup vs baseline: 1.1026x; 1.0178x over previous
//
#include <hip/hip_runtime.h>
#include <math.h>

#define T_SEQ 2048
#define D_MODEL 1024
#define NH 16
#define HD 64

typedef unsigned short ushort_t;
typedef unsigned int uint_t;
typedef short short8 __attribute__((ext_vector_type(8)));
typedef float floatx4 __attribute__((ext_vector_type(4)));

// ---- bf16 helpers (RNE) ----
__device__ __forceinline__ ushort_t f2bf(float f) {
    uint_t u = __float_as_uint(f);
    u += 0x7FFFu + ((u >> 16) & 1u);
    return (ushort_t)(u >> 16);
}
__device__ __forceinline__ uint_t pack2(float a, float b) {
    return (uint_t)f2bf(a) | ((uint_t)f2bf(b) << 16);
}
// async global -> LDS, 16B per lane (wave-uniform LDS base + lane*16)
__device__ __forceinline__ void gload16(const ushort_t* g, ushort_t* l) {
    __builtin_amdgcn_global_load_lds(
        (const __attribute__((address_space(1))) void*)g,
        (__attribute__((address_space(3))) void*)l, 16, 0, 0);
}

// ---------------------------------------------------------------------------
// Kernel 0: one-time fp32 -> bf16 convert of x, Wq, Wk, Wv, Wp.
// ---------------------------------------------------------------------------
__global__ __launch_bounds__(256) void to_bf16(
        const float* __restrict__ x,  const float* __restrict__ wq,
        const float* __restrict__ wk, const float* __restrict__ wv,
        const float* __restrict__ wp,
        ushort_t* __restrict__ xb,  ushort_t* __restrict__ wqb,
        ushort_t* __restrict__ wkb, ushort_t* __restrict__ wvb,
        ushort_t* __restrict__ wpb)
{
    size_t i = (size_t)blockIdx.x * 256 + threadIdx.x;
    const float* src; ushort_t* dst; size_t off;
    if (i < 262144)      { src = x;  dst = xb;  off = i; }
    else if (i < 393216) { src = wq; dst = wqb; off = i - 262144; }
    else if (i < 524288) { src = wk; dst = wkb; off = i - 393216; }
    else if (i < 655360) { src = wv; dst = wvb; off = i - 524288; }
    else                 { src = wp; dst = wpb; off = i - 655360; }
    float4 f0 = ((const float4*)src)[off * 2];
    float4 f1 = ((const float4*)src)[off * 2 + 1];
    uint4 u;
    u.x = pack2(f0.x, f0.y); u.y = pack2(f0.z, f0.w);
    u.z = pack2(f1.x, f1.y); u.w = pack2(f1.z, f1.w);
    ((uint4*)dst)[off] = u;
}

// ---------------------------------------------------------------------------
// Kernel 1: QKV GEMM (bf16 MFMA), BM=64 BN=128 BK=64, grid (8,32,3) = 768
// blocks = 3/CU. 2-phase dbuf, ds-read-first, ONE barrier/iter (unchanged
// from R10 — near its structural floor). XOR-swizzle staging.
// FUSED RMSNorm+RoPE (z<2) / V blend (z=2).
// ---------------------------------------------------------------------------
__global__ __launch_bounds__(256) void gemm_qkv(
        const ushort_t* __restrict__ xb,
        const ushort_t* __restrict__ Wqb, const ushort_t* __restrict__ Wkb,
        const ushort_t* __restrict__ Wvb,
        const float* __restrict__ vi, const float* __restrict__ lam,
        ushort_t* __restrict__ qb, ushort_t* __restrict__ kb,
        ushort_t* __restrict__ vbt)
{
    const int z = blockIdx.z;
    const ushort_t* __restrict__ W = (z == 0) ? Wqb : (z == 1) ? Wkb : Wvb;
    const int row0 = blockIdx.y * 64;
    const int col0 = blockIdx.x * 128;

    __shared__ ushort_t As[2 * 64 * 64];     // 16 KB (2 buffers)
    __shared__ ushort_t Bs[2 * 128 * 64];    // 32 KB

    const int tid = threadIdx.x;
    const int wave = tid >> 6, lane = tid & 63;
    const int wm = wave >> 1, wn = wave & 1;
    const int l15 = lane & 15, quad = lane >> 4;
    const int srow  = tid >> 3;                     // staging row 0..31
    const int sslot = (tid & 7) ^ (srow & 7);       // pre-swizzled 16B slot

    floatx4 acc[2][4];
    #pragma unroll
    for (int i = 0; i < 2; ++i)
        #pragma unroll
        for (int j = 0; j < 4; ++j)
            acc[i][j] = (floatx4){0.f, 0.f, 0.f, 0.f};

    // stage tile at k-offset k0 into buffer p (6 gloads/wave)
    auto stageAB = [&](int k0, int p) {
        ushort_t* Ap = As + p * 4096;
        ushort_t* Bp = Bs + p * 8192;
        #pragma unroll
        for (int c = 0; c < 2; ++c)
            gload16(xb + (size_t)(row0 + c * 32 + srow) * D_MODEL + k0 + sslot * 8,
                    Ap + c * 2048 + tid * 8);
        #pragma unroll
        for (int c = 0; c < 4; ++c)
            gload16(W + (size_t)(col0 + c * 32 + srow) * D_MODEL + k0 + sslot * 8,
                    Bp + c * 2048 + tid * 8);
    };

    stageAB(0, 0);
    int cur = 0;
    for (int k0 = 0; k0 < D_MODEL; k0 += 64) {
        asm volatile("s_waitcnt vmcnt(0)" ::: "memory");   // cur's 6 loads (1 iter old)
        __builtin_amdgcn_s_barrier();
        const ushort_t* Ac = As + cur * 4096;
        const ushort_t* Bc = Bs + cur * 8192;
        short8 a[2][2], b[2][4];
        #pragma unroll
        for (int kh = 0; kh < 2; ++kh) {
            const int slot = ((kh * 4 + quad) ^ (l15 & 7)) << 3;  // ushort offs
            #pragma unroll
            for (int i = 0; i < 2; ++i)
                a[kh][i] = *(const short8*)(Ac + (32 * wm + i * 16 + l15) * 64 + slot);
            #pragma unroll
            for (int j = 0; j < 4; ++j)
                b[kh][j] = *(const short8*)(Bc + (64 * wn + j * 16 + l15) * 64 + slot);
        }
        __builtin_amdgcn_sched_barrier(0);    // ds_reads stay above
        if (k0 + 64 < D_MODEL) stageAB(k0 + 64, cur ^ 1);
        __builtin_amdgcn_sched_barrier(0);    // gload issue stays above MFMAs
        #pragma unroll
        for (int kh = 0; kh < 2; ++kh)
            #pragma unroll
            for (int i = 0; i < 2; ++i)
                #pragma unroll
                for (int j = 0; j < 4; ++j)
                    acc[i][j] = __builtin_amdgcn_mfma_f32_16x16x32_bf16(a[kh][i], b[kh][j], acc[i][j], 0, 0, 0);
        cur ^= 1;
    }

    if (z < 2) {
        ushort_t* __restrict__ o = (z == 0) ? qb : kb;
        const float oscale = (z == 0) ? 0.125f : 1.0f;   // fold 1/sqrt(hd) into q
        const int hbase = col0 + 64 * wn;
        const float eps = 1.1920929e-7f;
        const float fr = exp2f(-10.0f * (float)l15 / 15.0f);  // rotating-pair freq
        #pragma unroll
        for (int i = 0; i < 2; ++i)
            #pragma unroll
            for (int r = 0; r < 4; ++r) {
                const int t = row0 + 32 * wm + i * 16 + quad * 4 + r;
                float v0 = acc[i][0][r], v1 = acc[i][1][r];
                float v2 = acc[i][2][r], v3 = acc[i][3][r];
                float ss = v0 * v0 + v1 * v1 + v2 * v2 + v3 * v3;
                ss += __shfl_xor(ss, 1);
                ss += __shfl_xor(ss, 2);
                ss += __shfl_xor(ss, 4);
                ss += __shfl_xor(ss, 8);
                const float sc = rsqrtf(ss * (1.0f / 64.0f) + eps);
                v0 *= sc; v1 *= sc; v2 *= sc; v3 *= sc;
                const float th = (float)t * fr;
                const float cs = cosf(th), sn = sinf(th);
                const float y0 = v0 * cs + v2 * sn;   // shown-source rotary sign
                const float y2 = v2 * cs - v0 * sn;
                const size_t rb = (size_t)t * D_MODEL + hbase;
                o[rb +  0 + l15] = f2bf(y0 * oscale);
                o[rb + 16 + l15] = f2bf(v1 * oscale);
                o[rb + 32 + l15] = f2bf(y2 * oscale);
                o[rb + 48 + l15] = f2bf(v3 * oscale);
            }
    } else {
        const float l0 = lam[0], l1 = lam[1];
        #pragma unroll
        for (int i = 0; i < 2; ++i)
            #pragma unroll
            for (int j = 0; j < 4; ++j) {
                const int tb = row0 + 32 * wm + i * 16 + quad * 4;
                const int jj = col0 + 64 * wn + j * 16 + l15;
                float b0 = l0 * acc[i][j][0] + l1 * vi[(size_t)(tb + 0) * D_MODEL + jj];
                float b1 = l0 * acc[i][j][1] + l1 * vi[(size_t)(tb + 1) * D_MODEL + jj];
                float b2 = l0 * acc[i][j][2] + l1 * vi[(size_t)(tb + 2) * D_MODEL + jj];
                float b3 = l0 * acc[i][j][3] + l1 * vi[(size_t)(tb + 3) * D_MODEL + jj];
                uint2 u;
                u.x = pack2(b0, b1);
                u.y = pack2(b2, b3);
                *(uint2*)(vbt + (size_t)jj * T_SEQ + tb) = u;   // [d][t]
            }
    }
}

// ---------------------------------------------------------------------------
// Kernel 2: MFMA flash attention. Change this round: stage-issue moved to the
// TOP of each KV iteration (right after the barrier, before the QK ds_reads)
// so the 4 prefetch loads are covered by the FULL iteration body (was only
// softmax+PV). Safe: top barrier of iter kt guarantees all waves finished
// reading buf cur^1 (last read at kt-1); R8/R9 equivalence showed no
// compiler alias-waits between DMA-issue and subsequent ds_reads.
// QPs [64][64] XOR slot-swizzled; LDS 40 KB = 4 blocks/CU; setprio on MFMA
// clusters; fixed-max softmax; rebalanced KV-split (makespan 14):
//   x in [ 0,28): 2-way chunks of qt = 27 - x/2      (sizes 8..14)
//   x in [28,40): 3-way chunks of qt = 28 + (x-28)/3 (sizes 9..11)
//   x in [40,54): direct qt = 53 - x                 (sizes 14..1, backfill)
// ---------------------------------------------------------------------------
__global__ __launch_bounds__(256) void attn(
        const ushort_t* __restrict__ qb, const ushort_t* __restrict__ kb,
        const ushort_t* __restrict__ vbt, ushort_t* __restrict__ yb,
        float* __restrict__ Opart, float* __restrict__ Lpart)
{
    const int h = blockIdx.x;
    const int x = blockIdx.y;
    int qt, ct_begin, ct_end, pidx;
    if (x < 28) {                       // 2-way, qt 27..14
        qt = 27 - (x >> 1);
        const int w = qt + 1;
        const int c0 = (w + 1) >> 1;
        if ((x & 1) == 0) { ct_begin = 0;  ct_end = c0; }
        else              { ct_begin = c0; ct_end = w;  }   // contains diag
        pidx = h * 40 + 12 + (qt - 14) * 2 + (x & 1);
    } else if (x < 40) {                // 3-way, qt 28..31
        const int xx = x - 28;
        qt = 28 + xx / 3;
        const int c = xx % 3;
        const int w = qt + 1;
        const int b0 = (w + 2) / 3;
        const int b1 = (2 * w + 2) / 3;
        ct_begin = (c == 0) ? 0  : (c == 1) ? b0 : b1;
        ct_end   = (c == 0) ? b0 : (c == 1) ? b1 : w;
        pidx = h * 40 + (qt - 28) * 3 + c;
    } else {                            // direct, qt 13..0
        qt = 53 - x;
        ct_begin = 0; ct_end = qt + 1;
        pidx = -1;
    }
    const int t0 = qt * 64;

    __shared__ ushort_t Ks[2 * 64 * 64];   // [s_local][d] linear, swizzled (16 KB)
    __shared__ ushort_t Vs[2 * 64 * 64];   // [d][s_local] linear, swizzled (16 KB)
    __shared__ ushort_t QPs[64 * 64];      // Q then P, XOR slot-swizzled (8 KB)

    const int tid = threadIdx.x;
    const int wave = tid >> 6, lane = tid & 63;
    const int l15 = lane & 15, quad = lane >> 4;
    const int srow  = tid >> 3;                   // staging row 0..31
    const int sslot = (tid & 7) ^ (srow & 7);     // pre-swizzled 16B slot
    const int bx = l15 & 7;

    // stage Q (64x64) once, swizzled: slot ^= row&7
    {
        const int r4 = tid >> 2, c4 = (tid & 3) * 16;
        const ushort_t* src = qb + (size_t)(t0 + r4) * D_MODEL + h * HD + c4;
        uint4 A = ((const uint4*)src)[0];
        uint4 B = ((const uint4*)src)[1];
        const int rs = r4 & 7;
        const int s0 = (c4 >> 3) ^ rs;        // c4>>3 is even
        const int s1 = ((c4 >> 3) + 1) ^ rs;
        *(uint4*)(QPs + r4 * 64 + s0 * 8) = A;
        *(uint4*)(QPs + r4 * 64 + s1 * 8) = B;
    }
    __syncthreads();
    short8 qf[2];
    qf[0] = *(const short8*)(QPs + (16 * wave + l15) * 64 + ((quad ^ bx) << 3));
    qf[1] = *(const short8*)(QPs + (16 * wave + l15) * 64 + (((quad + 4) ^ bx) << 3));

    auto stageKV = [&](int kt, int p) {
        const int s0 = kt * 64;
        ushort_t* Kp = Ks + p * 4096;
        ushort_t* Vp = Vs + p * 4096;
        gload16(kb  + (size_t)(s0 + srow)      * D_MODEL + h * HD + sslot * 8, Kp + tid * 8);
        gload16(kb  + (size_t)(s0 + 32 + srow) * D_MODEL + h * HD + sslot * 8, Kp + 2048 + tid * 8);
        gload16(vbt + (size_t)(h * HD + srow)      * T_SEQ + s0 + sslot * 8,   Vp + tid * 8);
        gload16(vbt + (size_t)(h * HD + 32 + srow) * T_SEQ + s0 + sslot * 8,   Vp + 2048 + tid * 8);
    };

    float l_acc[4];
    floatx4 O[4];
    #pragma unroll
    for (int r = 0; r < 4; ++r) l_acc[r] = 0.0f;
    #pragma unroll
    for (int d = 0; d < 4; ++d) O[d] = (floatx4){0.f, 0.f, 0.f, 0.f};

    stageKV(ct_begin, 0);
    int cur = 0;
    for (int kt = ct_begin; kt < ct_end; ++kt) {
        asm volatile("s_waitcnt vmcnt(0)" ::: "memory");  // cur's 4 loads done
        __builtin_amdgcn_s_barrier();                     // all waves past iter kt-1

        // issue next-tile prefetch FIRST: covered by the full iteration body
        if (kt + 1 < ct_end) stageKV(kt + 1, cur ^ 1);    // safe: cur^1 last read
        __builtin_amdgcn_sched_barrier(0);                // at kt-1, fenced above

        const ushort_t* Kc = Ks + cur * 4096;
        const ushort_t* Vc = Vs + cur * 4096;

        floatx4 sa[4];
        __builtin_amdgcn_s_setprio(1);
        #pragma unroll
        for (int ct = 0; ct < 4; ++ct) {
            const ushort_t* krow = Kc + (ct * 16 + l15) * 64;
            short8 b0 = *(const short8*)(krow + ((quad ^ bx) << 3));
            short8 b1 = *(const short8*)(krow + (((quad + 4) ^ bx) << 3));
            floatx4 t4 = (floatx4){0.f, 0.f, 0.f, 0.f};
            t4 = __builtin_amdgcn_mfma_f32_16x16x32_bf16(qf[0], b0, t4, 0, 0, 0);
            t4 = __builtin_amdgcn_mfma_f32_16x16x32_bf16(qf[1], b1, t4, 0, 0, 0);
            sa[ct] = t4;
        }
        __builtin_amdgcn_s_setprio(0);

        if (kt == qt) {   // causal mask on the diagonal tile
            #pragma unroll
            for (int ct = 0; ct < 4; ++ct)
                #pragma unroll
                for (int r = 0; r < 4; ++r) {
                    int trow = 16 * wave + quad * 4 + r;
                    int scol = ct * 16 + l15;
                    if (scol > trow) sa[ct][r] = -1e30f;
                }
        }
        // fixed-max softmax: p = exp(s - 8), per-lane l accumulation only
        float p[4][4];
        #pragma unroll
        for (int ct = 0; ct < 4; ++ct)
            #pragma unroll
            for (int r = 0; r < 4; ++r) {
                p[ct][r] = __expf(sa[ct][r] - 8.0f);
                l_acc[r] += p[ct][r];
            }

        // P -> LDS (wave-private 16-row stripe; swizzled; no barrier needed)
        #pragma unroll
        for (int ct = 0; ct < 4; ++ct)
            #pragma unroll
            for (int r = 0; r < 4; ++r) {
                const int row = 16 * wave + quad * 4 + r;
                const int ps = (ct * 2 + (l15 >> 3)) ^ (row & 7);
                QPs[row * 64 + ps * 8 + (l15 & 7)] = f2bf(p[ct][r]);
            }

        short8 pa0 = *(const short8*)(QPs + (16 * wave + l15) * 64 + ((quad ^ bx) << 3));
        short8 pa1 = *(const short8*)(QPs + (16 * wave + l15) * 64 + (((quad + 4) ^ bx) << 3));
        __builtin_amdgcn_s_setprio(1);
        #pragma unroll
        for (int dt = 0; dt < 4; ++dt) {
            const ushort_t* vrow = Vc + (dt * 16 + l15) * 64;
            short8 vb0 = *(const short8*)(vrow + ((quad ^ bx) << 3));
            short8 vb1 = *(const short8*)(vrow + (((quad + 4) ^ bx) << 3));
            O[dt] = __builtin_amdgcn_mfma_f32_16x16x32_bf16(pa0, vb0, O[dt], 0, 0, 0);
            O[dt] = __builtin_amdgcn_mfma_f32_16x16x32_bf16(pa1, vb1, O[dt], 0, 0, 0);
        }
        __builtin_amdgcn_s_setprio(0);
        cur ^= 1;
    }

    // one-time row-sum reduce across the 16 col-lanes
    float l_run[4];
    #pragma unroll
    for (int r = 0; r < 4; ++r) {
        float s = l_acc[r];
        s += __shfl_xor(s, 1);
        s += __shfl_xor(s, 2);
        s += __shfl_xor(s, 4);
        s += __shfl_xor(s, 8);
        l_run[r] = s;
    }

    if (pidx < 0) {
        // direct: normalize and write bf16
        #pragma unroll
        for (int r = 0; r < 4; ++r) {
            const float inv_l = 1.0f / l_run[r];
            const int t = t0 + 16 * wave + quad * 4 + r;
            #pragma unroll
            for (int dt = 0; dt < 4; ++dt)
                yb[(size_t)t * D_MODEL + h * HD + dt * 16 + l15] = f2bf(O[dt][r] * inv_l);
        }
    } else {
        // partial: unnormalized fp32 O + per-row l (fixed max => no m needed)
        float* __restrict__ Op = Opart + (size_t)pidx * 4096;
        #pragma unroll
        for (int r = 0; r < 4; ++r) {
            const int row = 16 * wave + quad * 4 + r;
            #pragma unroll
            for (int dt = 0; dt < 4; ++dt)
                Op[row * 64 + dt * 16 + l15] = O[dt][r];
            if (l15 == 0) Lpart[(size_t)pidx * 64 + row] = l_run[r];
        }
    }
}

// ---------------------------------------------------------------------------
// Kernel 2b: combine the 2 or 3 KV-chunk partials for qt in [14,32).
// Fixed max on all chunks => combined = (sum O_c) / (sum l_c).
// grid = (16 h, 18 qt-14). Thread = one (row, 16-col segment).
// ---------------------------------------------------------------------------
__global__ __launch_bounds__(256) void attn_combine(
        const float* __restrict__ Opart, const float* __restrict__ Lpart,
        ushort_t* __restrict__ yb)
{
    const int h  = blockIdx.x;
    const int qt = 14 + (int)blockIdx.y;   // 14..31
    const int tid = threadIdx.x;
    const int row  = tid >> 2;           // 0..63
    const int dseg = (tid & 3) * 16;     // 0/16/32/48
    int s0, nc;
    if (qt >= 28) { s0 = (qt - 28) * 3;        nc = 3; }
    else          { s0 = 12 + (qt - 14) * 2;   nc = 2; }
    const int p0 = h * 40 + s0;

    float accv[16];
    #pragma unroll
    for (int e = 0; e < 16; ++e) accv[e] = 0.0f;
    float lsum = 0.0f;
    for (int c = 0; c < nc; ++c) {
        const float* Op = Opart + (size_t)(p0 + c) * 4096 + row * 64 + dseg;
        lsum += Lpart[(size_t)(p0 + c) * 64 + row];
        #pragma unroll
        for (int g = 0; g < 4; ++g) {
            float4 a = ((const float4*)Op)[g];
            accv[g * 4 + 0] += a.x;
            accv[g * 4 + 1] += a.y;
            accv[g * 4 + 2] += a.z;
            accv[g * 4 + 3] += a.w;
        }
    }
    const float inv = 1.0f / lsum;

    uint_t u[8];
    #pragma unroll
    for (int g = 0; g < 4; ++g) {
        u[g * 2 + 0] = pack2(accv[g * 4 + 0] * inv, accv[g * 4 + 1] * inv);
        u[g * 2 + 1] = pack2(accv[g * 4 + 2] * inv, accv[g * 4 + 3] * inv);
    }
    const int t = qt * 64 + row;
    uint4* dst = (uint4*)(yb + (size_t)t * D_MODEL + h * HD + dseg);
    dst[0] = make_uint4(u[0], u[1], u[2], u[3]);
    dst[1] = make_uint4(u[4], u[5], u[6], u[7]);
}

// ---------------------------------------------------------------------------
// Kernel 3: output projection, BM=64 BN=64 BK=64, grid (16,32) = 512 blocks
// = 2/CU (was 256 = 1/CU: worst occupancy in the pipeline). 4 row-stripe
// waves, each 16 rows x 64 cols, acc[4]. LDS 32 KB (2 bufs of A8K+B8K).
// Same ds-read-first 2-phase dbuf. fp32 out.
// ---------------------------------------------------------------------------
__global__ __launch_bounds__(256) void gemm_proj(
        const ushort_t* __restrict__ yb, const ushort_t* __restrict__ Wpb,
        float* __restrict__ out)
{
    const int row0 = blockIdx.y * 64;
    const int col0 = blockIdx.x * 64;

    __shared__ ushort_t As[2 * 64 * 64];   // 16 KB
    __shared__ ushort_t Bs[2 * 64 * 64];   // 16 KB

    const int tid = threadIdx.x;
    const int wave = tid >> 6, lane = tid & 63;
    const int l15 = lane & 15, quad = lane >> 4;
    const int srow  = tid >> 3;
    const int sslot = (tid & 7) ^ (srow & 7);

    floatx4 acc4[4];
    #pragma unroll
    for (int j = 0; j < 4; ++j)
        acc4[j] = (floatx4){0.f, 0.f, 0.f, 0.f};

    // stage tile at k-offset k0 into buffer p (4 gloads/thread)
    auto stageAB = [&](int k0, int p) {
        ushort_t* Ap = As + p * 4096;
        ushort_t* Bp = Bs + p * 4096;
        #pragma unroll
        for (int c = 0; c < 2; ++c)
            gload16(yb + (size_t)(row0 + c * 32 + srow) * D_MODEL + k0 + sslot * 8,
                    Ap + c * 2048 + tid * 8);
        #pragma unroll
        for (int c = 0; c < 2; ++c)
            gload16(Wpb + (size_t)(col0 + c * 32 + srow) * D_MODEL + k0 + sslot * 8,
                    Bp + c * 2048 + tid * 8);
    };

    stageAB(0, 0);
    int cur = 0;
    for (int k0 = 0; k0 < D_MODEL; k0 += 64) {
        asm volatile("s_waitcnt vmcnt(0)" ::: "memory");
        __builtin_amdgcn_s_barrier();
        const ushort_t* Ac = As + cur * 4096;
        const ushort_t* Bc = Bs + cur * 4096;
        short8 a[2], b[2][4];
        #pragma unroll
        for (int kh = 0; kh < 2; ++kh) {
            const int slot = ((kh * 4 + quad) ^ (l15 & 7)) << 3;
            a[kh] = *(const short8*)(Ac + (16 * wave + l15) * 64 + slot);
            #pragma unroll
            for (int j = 0; j < 4; ++j)
                b[kh][j] = *(const short8*)(Bc + (j * 16 + l15) * 64 + slot);
        }
        __builtin_amdgcn_sched_barrier(0);
        if (k0 + 64 < D_MODEL) stageAB(k0 + 64, cur ^ 1);
        __builtin_amdgcn_sched_barrier(0);
        #pragma unroll
        for (int kh = 0; kh < 2; ++kh)
            #pragma unroll
            for (int j = 0; j < 4; ++j)
                acc4[j] = __builtin_amdgcn_mfma_f32_16x16x32_bf16(a[kh], b[kh][j], acc4[j], 0, 0, 0);
        cur ^= 1;
    }

    #pragma unroll
    for (int j = 0; j < 4; ++j) {
        const int t = row0 + 16 * wave + quad * 4;
        const int jj = col0 + j * 16 + l15;
        #pragma unroll
        for (int r = 0; r < 4; ++r)
            out[(size_t)(t + r) * D_MODEL + jj] = acc4[j][r];
    }
}

// ---------------------------------------------------------------------------
extern "C" void kernel_launch(void* const* d_in, const int* in_sizes, int n_in,
                              void* d_out, int out_size, void* d_ws, size_t ws_size,
                              hipStream_t stream) {
    (void)in_sizes; (void)n_in; (void)out_size; (void)ws_size;
    const float* x   = (const float*)d_in[0];
    const float* vi  = (const float*)d_in[1];
    const float* Wq  = (const float*)d_in[2];
    const float* Wk  = (const float*)d_in[3];
    const float* Wv  = (const float*)d_in[4];
    const float* Wp  = (const float*)d_in[5];
    const float* lam = (const float*)d_in[6];

    char* base = (char*)d_ws;                                  // 28 MiB used
    ushort_t* xb  = (ushort_t*)(base);                         // [ 0, 4) MiB (dead after gemm_qkv)
    ushort_t* wqb = (ushort_t*)(base + (size_t)4  * 1048576);  // [ 4, 6)  (dead after gemm_qkv)
    ushort_t* wkb = (ushort_t*)(base + (size_t)6  * 1048576);  // [ 6, 8)  (dead after gemm_qkv)
    ushort_t* wvb = (ushort_t*)(base + (size_t)8  * 1048576);  // [ 8,10)  (dead after gemm_qkv)
    ushort_t* wpb = (ushort_t*)(base + (size_t)10 * 1048576);  // [10,12)  (live until gemm_proj)
    ushort_t* qb  = (ushort_t*)(base + (size_t)12 * 1048576);  // [12,16)
    ushort_t* kb  = (ushort_t*)(base + (size_t)16 * 1048576);  // [16,20)
    ushort_t* vbt = (ushort_t*)(base + (size_t)20 * 1048576);  // [20,24)  [d][t]
    ushort_t* yb  = (ushort_t*)(base + (size_t)24 * 1048576);  // [24,28)
    // attn partials: Opart = 640 * 16 KB = 10 MiB in dead [0,10) region;
    // Lpart = 640 * 64 * 4B = 160 KB in d_out (scratch until gemm_proj).
    float* Opart  = (float*)(base);
    float* Lpart  = (float*)d_out;
    float* out = (float*)d_out;

    to_bf16<<<dim3(786432 / 256), 256, 0, stream>>>(x, Wq, Wk, Wv, Wp, xb, wqb, wkb, wvb, wpb);
    gemm_qkv<<<dim3(8, 32, 3), 256, 0, stream>>>(xb, wqb, wkb, wvb, vi, lam, qb, kb, vbt);
    attn<<<dim3(16, 54), 256, 0, stream>>>(qb, kb, vbt, yb, Opart, Lpart);
    attn_combine<<<dim3(16, 18), 256, 0, stream>>>(Opart, Lpart, yb);
    gemm_proj<<<dim3(16, 32), 256, 0, stream>>>(yb, wpb, out);
}